// Round 13
// baseline (361.217 us; speedup 1.0000x reference)
//
#include <hip/hip_runtime.h>
#include <hip/hip_bf16.h>
#include <math.h>

#define N_NODES 50000
#define N_EDGES 1600000
#define H 64
#define G_GRAPHS 512
#define C_CLS 2
#define BN_EPS 1e-5f
#define NBUCK 196           // buckets of 256 nodes: dst>>8 in [0,196)
#define E4 (N_EDGES / 4)    // 400000
#define CSR_BLOCKS ((E4 + 511) / 512)   // 782
#define IOP 72              // padded LDS row stride (bf16) for conflict-free b128
#define NPB 128             // nodes per fused block (8 waves x 16)

typedef __attribute__((ext_vector_type(8))) short short8;
typedef __attribute__((ext_vector_type(4))) float floatx4;

__device__ __forceinline__ float bflo(unsigned int u) { return __uint_as_float(u << 16); }
__device__ __forceinline__ float bfhi(unsigned int u) { return __uint_as_float(u & 0xffff0000u); }
__device__ __forceinline__ unsigned int bf16_rne(float f) {
    unsigned int u = __float_as_uint(f);
    u += 0x7fffu + ((u >> 16) & 1u);
    return u >> 16;
}

// ---------- prep: transpose 5 weight matrices to bf16 wT[j*64+k]; pack x ----------
__global__ __launch_bounds__(256) void prep_kernel(
    const float* __restrict__ w2_0, const float* __restrict__ w1_1,
    const float* __restrict__ w2_1, const float* __restrict__ w1_2,
    const float* __restrict__ w2_2, unsigned short* __restrict__ wt,
    const float* __restrict__ x, uint2* __restrict__ xb) {
    int b = blockIdx.x, t = threadIdx.x;
    if (b < 5) {
        const float* w = (b == 0) ? w2_0 : (b == 1) ? w1_1 : (b == 2) ? w2_1
                         : (b == 3) ? w1_2 : w2_2;
        unsigned short* o = wt + b * (H * H);
        for (int idx = t; idx < H * H; idx += 256) {
            int k = idx >> 6, j = idx & 63;
            o[j * H + k] = (unsigned short)bf16_rne(w[idx]);
        }
    } else {
        int node = (b - 5) * 256 + t;
        if (node < N_NODES) {
            uint2 p;
            p.x = bf16_rne(x[node * 3 + 0]) | (bf16_rne(x[node * 3 + 1]) << 16);
            p.y = bf16_rne(x[node * 3 + 2]);
            xb[node] = p;
        }
    }
}

// ---------- CSR pass 1: global bucket histogram (LDS-privatized) ----------
__global__ __launch_bounds__(256) void bhist_kernel(const int* __restrict__ dst,
                                                    int* __restrict__ gbh) {
    __shared__ int bh[NBUCK];
    int t = threadIdx.x;
    if (t < NBUCK) bh[t] = 0;
    __syncthreads();
    int base = blockIdx.x * 512;
#pragma unroll
    for (int p = 0; p < 2; p++) {
        int i = base + p * 256 + t;
        if (i < E4) {
            int4 d = ((const int4*)dst)[i];
            atomicAdd(&bh[d.x >> 8], 1);
            atomicAdd(&bh[d.y >> 8], 1);
            atomicAdd(&bh[d.z >> 8], 1);
            atomicAdd(&bh[d.w >> 8], 1);
        }
    }
    __syncthreads();
    if (t < NBUCK && bh[t]) atomicAdd(&gbh[t], bh[t]);
}

// ---------- CSR pass 2: exclusive scan of 196 bucket counts ----------
__global__ __launch_bounds__(256) void bscan_kernel(const int* __restrict__ gbh,
                                                    int* __restrict__ bucket_start,
                                                    int* __restrict__ cursor,
                                                    int* __restrict__ row_start) {
    __shared__ int s[256];
    int t = threadIdx.x;
    int v = (t < NBUCK) ? gbh[t] : 0;
    s[t] = v;
    __syncthreads();
    for (int off = 1; off < 256; off <<= 1) {
        int u = 0;
        if (t >= off) u = s[t - off];
        __syncthreads();
        if (t >= off) s[t] += u;
        __syncthreads();
    }
    int excl = s[t] - v;
    if (t < NBUCK) { bucket_start[t] = excl; cursor[t] = excl; }
    if (t == 0) { bucket_start[NBUCK] = N_EDGES; row_start[N_NODES] = N_EDGES; }
}

// ---------- CSR pass 3: scatter edges into buckets (rank via LDS atomics) ----------
__global__ __launch_bounds__(256) void bscatter_kernel(const int* __restrict__ src,
                                                       const int* __restrict__ dst,
                                                       int* __restrict__ cursor,
                                                       int* __restrict__ gpacked) {
    __shared__ int bh[NBUCK];
    int t = threadIdx.x;
    if (t < NBUCK) bh[t] = 0;
    __syncthreads();
    int base = blockIdx.x * 512;

    int pkA[4], bkA[4], lrA[4]; bool vA = false;
    int pkB[4], bkB[4], lrB[4]; bool vB = false;
    {
        int i = base + t;
        if (i < E4) {
            vA = true;
            int4 s4 = ((const int4*)src)[i];
            int4 d4 = ((const int4*)dst)[i];
            bkA[0] = d4.x >> 8; pkA[0] = ((d4.x & 255) << 16) | s4.x; lrA[0] = atomicAdd(&bh[bkA[0]], 1);
            bkA[1] = d4.y >> 8; pkA[1] = ((d4.y & 255) << 16) | s4.y; lrA[1] = atomicAdd(&bh[bkA[1]], 1);
            bkA[2] = d4.z >> 8; pkA[2] = ((d4.z & 255) << 16) | s4.z; lrA[2] = atomicAdd(&bh[bkA[2]], 1);
            bkA[3] = d4.w >> 8; pkA[3] = ((d4.w & 255) << 16) | s4.w; lrA[3] = atomicAdd(&bh[bkA[3]], 1);
        }
    }
    {
        int i = base + 256 + t;
        if (i < E4) {
            vB = true;
            int4 s4 = ((const int4*)src)[i];
            int4 d4 = ((const int4*)dst)[i];
            bkB[0] = d4.x >> 8; pkB[0] = ((d4.x & 255) << 16) | s4.x; lrB[0] = atomicAdd(&bh[bkB[0]], 1);
            bkB[1] = d4.y >> 8; pkB[1] = ((d4.y & 255) << 16) | s4.y; lrB[1] = atomicAdd(&bh[bkB[1]], 1);
            bkB[2] = d4.z >> 8; pkB[2] = ((d4.z & 255) << 16) | s4.z; lrB[2] = atomicAdd(&bh[bkB[2]], 1);
            bkB[3] = d4.w >> 8; pkB[3] = ((d4.w & 255) << 16) | s4.w; lrB[3] = atomicAdd(&bh[bkB[3]], 1);
        }
    }
    __syncthreads();
    if (t < NBUCK) {
        int c = bh[t];
        bh[t] = c ? atomicAdd(&cursor[t], c) : 0;
    }
    __syncthreads();
    if (vA) {
#pragma unroll
        for (int q = 0; q < 4; q++) gpacked[bh[bkA[q]] + lrA[q]] = pkA[q];
    }
    if (vB) {
#pragma unroll
        for (int q = 0; q < 4; q++) gpacked[bh[bkB[q]] + lrB[q]] = pkB[q];
    }
}

// ---------- CSR pass 4: per-bucket local CSR (256 nodes/bucket) ----------
__global__ __launch_bounds__(256) void bcsr_kernel(const int* __restrict__ gpacked,
                                                   const int* __restrict__ bucket_start,
                                                   int* __restrict__ row_start,
                                                   int* __restrict__ edge_src) {
    __shared__ int cnt[256];
    __shared__ int pref[256];
    int b = blockIdx.x;
    int t = threadIdx.x;
    int bs = bucket_start[b], be = bucket_start[b + 1];
    cnt[t] = 0;
    __syncthreads();
    for (int i = bs + t; i < be; i += 256) atomicAdd(&cnt[gpacked[i] >> 16], 1);
    __syncthreads();
    int v = cnt[t];
    pref[t] = v;
    __syncthreads();
    for (int off = 1; off < 256; off <<= 1) {
        int u = 0;
        if (t >= off) u = pref[t - off];
        __syncthreads();
        if (t >= off) pref[t] += u;
        __syncthreads();
    }
    int excl = pref[t] - v;
    int node = b * 256 + t;
    if (node < N_NODES) row_start[node] = bs + excl;
    cnt[t] = excl;
    __syncthreads();
    for (int i = bs + t; i < be; i += 256) {
        int p = gpacked[i];
        int pos = atomicAdd(&cnt[p >> 16], 1);
        edge_src[bs + pos] = p & 0xffff;
    }
}

// ---------- layer 1 fused: gather3 + lin1+BN+relu (per-lane) + MFMA lin2 ----------
// 8 waves x 16 nodes, no __syncthreads (all LDS is wave-private).
__global__ __launch_bounds__(512) void gin1_fused_kernel(
    const float* __restrict__ x, const uint2* __restrict__ xb,
    const int* __restrict__ row_start, const int* __restrict__ edge_src,
    const float* __restrict__ w1, const float* __restrict__ b1,
    const float* __restrict__ bn_g, const float* __restrict__ bn_b,
    const float* __restrict__ bn_m, const float* __restrict__ bn_v,
    const unsigned short* __restrict__ w2t, const float* __restrict__ b2,
    __hip_bfloat16* __restrict__ hout) {
    __shared__ unsigned short s_mid[8][16 * IOP];
    __shared__ unsigned short s_out[8][16 * IOP];

    int tid = threadIdx.x;
    int wave = tid >> 6, j = tid & 63;
    int quad = j >> 4, l15 = j & 15;
    int nodebase = blockIdx.x * NPB + wave * 16;

    // hoisted per-lane constants
    float wj0 = w1[j], wj1 = w1[H + j], wj2 = w1[2 * H + j];
    float sc = rsqrtf(bn_v[j] + BN_EPS) * bn_g[j];
    float sh = bn_b[j] - bn_m[j] * sc;
    float bj = b1[j];
    float bb2[4];
#pragma unroll
    for (int jt = 0; jt < 4; jt++) bb2[jt] = b2[jt * 16 + l15];

    unsigned short* mid = s_mid[wave];
    unsigned short* outw = s_out[wave];

    // phase A: gather + first linear for this wave's 16 nodes
    for (int nl = 0; nl < 16; nl++) {
        int node = min(nodebase + nl, N_NODES - 1);
        int rs = row_start[node], re = row_start[node + 1];
        float a0 = 0.f, a1 = 0.f, a2 = 0.f;
        for (int t = rs + j; t < re; t += 64) {
            uint2 p = xb[edge_src[t]];
            a0 += bflo(p.x); a1 += bfhi(p.x); a2 += bflo(p.y);
        }
#pragma unroll
        for (int off = 32; off > 0; off >>= 1) {
            a0 += __shfl_xor(a0, off);
            a1 += __shfl_xor(a1, off);
            a2 += __shfl_xor(a2, off);
        }
        float in0 = a0 + x[node * 3 + 0];
        float in1 = a1 + x[node * 3 + 1];
        float in2 = a2 + x[node * 3 + 2];
        float m = bj + in0 * wj0 + in1 * wj1 + in2 * wj2;
        m = fmaxf(m * sc + sh, 0.f);
        mid[nl * IOP + j] = (unsigned short)bf16_rne(m);
    }

    // phase B: 16x64 @ 64x64 second matmul via MFMA (wave-local)
    short8 m0 = *(const short8*)&mid[l15 * IOP + quad * 8];
    short8 m1 = *(const short8*)&mid[l15 * IOP + quad * 8 + 32];
#pragma unroll
    for (int jt = 0; jt < 4; jt++) {
        short8 b0 = *(const short8*)&w2t[(jt * 16 + l15) * H + quad * 8];
        short8 bv = *(const short8*)&w2t[(jt * 16 + l15) * H + quad * 8 + 32];
        floatx4 c = {0.f, 0.f, 0.f, 0.f};
        c = __builtin_amdgcn_mfma_f32_16x16x32_bf16(m0, b0, c, 0, 0, 0);
        c = __builtin_amdgcn_mfma_f32_16x16x32_bf16(m1, bv, c, 0, 0, 0);
#pragma unroll
        for (int r = 0; r < 4; r++) {
            float v = fmaxf(c[r] + bb2[jt], 0.f);
            outw[(quad * 4 + r) * IOP + jt * 16 + l15] = (unsigned short)bf16_rne(v);
        }
    }

    // coalesced store (guarded)
    unsigned short* ho = (unsigned short*)hout;
#pragma unroll
    for (int cc = 0; cc < 2; cc++) {
        int r = cc * 8 + (j >> 3);
        int node = nodebase + r;
        if (node < N_NODES) {
            short8 v = *(const short8*)&outw[r * IOP + (j & 7) * 8];
            *(short8*)(ho + (size_t)node * H + (j & 7) * 8) = v;
        }
    }
}

// ---------- layers 2/3 fused: gather(dwordx4) + full MFMA MLP, no barriers ----------
__global__ __launch_bounds__(512) void gin_fused_kernel(
    const __hip_bfloat16* __restrict__ hin, const int* __restrict__ row_start,
    const int* __restrict__ edge_src,
    const unsigned short* __restrict__ w1t, const float* __restrict__ b1,
    const float* __restrict__ bn_g, const float* __restrict__ bn_b,
    const float* __restrict__ bn_m, const float* __restrict__ bn_v,
    const unsigned short* __restrict__ w2t, const float* __restrict__ b2,
    __hip_bfloat16* __restrict__ hout) {
    __shared__ unsigned short s_xs[8][16 * IOP];
    __shared__ unsigned short s_mid[8][16 * IOP];

    int tid = threadIdx.x;
    int wave = tid >> 6, j = tid & 63;
    int o = j >> 3, jo = j & 7;          // gather: edge-of-8, feature-octet
    int quad = j >> 4, l15 = j & 15;     // mfma lane coords
    int nodebase = blockIdx.x * NPB + wave * 16;

    // hoisted per-lane BN/bias constants (L2 reads)
    float scl[4], sht[4], bb1[4], bb2[4];
#pragma unroll
    for (int jt = 0; jt < 4; jt++) {
        int jj = jt * 16 + l15;
        float sc = rsqrtf(bn_v[jj] + BN_EPS) * bn_g[jj];
        scl[jt] = sc;
        sht[jt] = bn_b[jj] - bn_m[jj] * sc;
        bb1[jt] = b1[jj];
        bb2[jt] = b2[jj];
    }

    unsigned short* xsw = s_xs[wave];
    unsigned short* mid = s_mid[wave];
    const char* hb = (const char*)hin;

    // phase A: gather this wave's 16 nodes into wave-private LDS
    for (int nl = 0; nl < 16; nl++) {
        int node = min(nodebase + nl, N_NODES - 1);
        int rs = row_start[node], re = row_start[node + 1];
        float a0 = 0.f, a1 = 0.f, a2 = 0.f, a3 = 0.f, a4 = 0.f, a5 = 0.f, a6 = 0.f, a7 = 0.f;
        for (int base = rs; base < re; base += 64) {
            int idx = base + j;
            int sv = (idx < re) ? edge_src[idx] : 0;
            int cnt = min(64, re - base);
            int i = 0;
            for (; i + 8 <= cnt; i += 8) {
                int s = __shfl(sv, i + o);
                uint4 raw = *(const uint4*)(hb + (size_t)s * 128 + jo * 16);
                a0 += bflo(raw.x); a1 += bfhi(raw.x);
                a2 += bflo(raw.y); a3 += bfhi(raw.y);
                a4 += bflo(raw.z); a5 += bfhi(raw.z);
                a6 += bflo(raw.w); a7 += bfhi(raw.w);
            }
            if (i < cnt) {
                int r = cnt - i;
                int s = __shfl(sv, i + (o < r ? o : 0));
                uint4 raw = *(const uint4*)(hb + (size_t)s * 128 + jo * 16);
                if (o < r) {
                    a0 += bflo(raw.x); a1 += bfhi(raw.x);
                    a2 += bflo(raw.y); a3 += bfhi(raw.y);
                    a4 += bflo(raw.z); a5 += bfhi(raw.z);
                    a6 += bflo(raw.w); a7 += bfhi(raw.w);
                }
            }
        }
        a0 += __shfl_xor(a0, 8); a0 += __shfl_xor(a0, 16); a0 += __shfl_xor(a0, 32);
        a1 += __shfl_xor(a1, 8); a1 += __shfl_xor(a1, 16); a1 += __shfl_xor(a1, 32);
        a2 += __shfl_xor(a2, 8); a2 += __shfl_xor(a2, 16); a2 += __shfl_xor(a2, 32);
        a3 += __shfl_xor(a3, 8); a3 += __shfl_xor(a3, 16); a3 += __shfl_xor(a3, 32);
        a4 += __shfl_xor(a4, 8); a4 += __shfl_xor(a4, 16); a4 += __shfl_xor(a4, 32);
        a5 += __shfl_xor(a5, 8); a5 += __shfl_xor(a5, 16); a5 += __shfl_xor(a5, 32);
        a6 += __shfl_xor(a6, 8); a6 += __shfl_xor(a6, 16); a6 += __shfl_xor(a6, 32);
        a7 += __shfl_xor(a7, 8); a7 += __shfl_xor(a7, 16); a7 += __shfl_xor(a7, 32);
        if (o == 0) {
            uint4 raw = *(const uint4*)(hb + (size_t)node * 128 + jo * 16);
            a0 += bflo(raw.x); a1 += bfhi(raw.x);
            a2 += bflo(raw.y); a3 += bfhi(raw.y);
            a4 += bflo(raw.z); a5 += bfhi(raw.z);
            a6 += bflo(raw.w); a7 += bfhi(raw.w);
            uint4 ov;
            ov.x = bf16_rne(a0) | (bf16_rne(a1) << 16);
            ov.y = bf16_rne(a2) | (bf16_rne(a3) << 16);
            ov.z = bf16_rne(a4) | (bf16_rne(a5) << 16);
            ov.w = bf16_rne(a6) | (bf16_rne(a7) << 16);
            *(uint4*)&xsw[nl * IOP + jo * 8] = ov;
        }
    }

    // phase B: MLP via MFMA (wave-local; compiler inserts lgkmcnt before use)
    short8 a0 = *(const short8*)&xsw[l15 * IOP + quad * 8];
    short8 a1 = *(const short8*)&xsw[l15 * IOP + quad * 8 + 32];
#pragma unroll
    for (int jt = 0; jt < 4; jt++) {
        short8 b0 = *(const short8*)&w1t[(jt * 16 + l15) * H + quad * 8];
        short8 bv = *(const short8*)&w1t[(jt * 16 + l15) * H + quad * 8 + 32];
        floatx4 c = {0.f, 0.f, 0.f, 0.f};
        c = __builtin_amdgcn_mfma_f32_16x16x32_bf16(a0, b0, c, 0, 0, 0);
        c = __builtin_amdgcn_mfma_f32_16x16x32_bf16(a1, bv, c, 0, 0, 0);
#pragma unroll
        for (int r = 0; r < 4; r++) {
            float v = (c[r] + bb1[jt]) * scl[jt] + sht[jt];
            v = fmaxf(v, 0.f);
            mid[(quad * 4 + r) * IOP + jt * 16 + l15] = (unsigned short)bf16_rne(v);
        }
    }

    short8 m0 = *(const short8*)&mid[l15 * IOP + quad * 8];
    short8 m1 = *(const short8*)&mid[l15 * IOP + quad * 8 + 32];
#pragma unroll
    for (int jt = 0; jt < 4; jt++) {
        short8 b0 = *(const short8*)&w2t[(jt * 16 + l15) * H + quad * 8];
        short8 bv = *(const short8*)&w2t[(jt * 16 + l15) * H + quad * 8 + 32];
        floatx4 c = {0.f, 0.f, 0.f, 0.f};
        c = __builtin_amdgcn_mfma_f32_16x16x32_bf16(m0, b0, c, 0, 0, 0);
        c = __builtin_amdgcn_mfma_f32_16x16x32_bf16(m1, bv, c, 0, 0, 0);
#pragma unroll
        for (int r = 0; r < 4; r++) {
            float v = fmaxf(c[r] + bb2[jt], 0.f);
            xsw[(quad * 4 + r) * IOP + jt * 16 + l15] = (unsigned short)bf16_rne(v);  // reuse s_xs
        }
    }

    // coalesced store (guarded)
    unsigned short* ho = (unsigned short*)hout;
#pragma unroll
    for (int cc = 0; cc < 2; cc++) {
        int r = cc * 8 + (j >> 3);
        int node = nodebase + r;
        if (node < N_NODES) {
            short8 v = *(const short8*)&xsw[r * IOP + (j & 7) * 8];
            *(short8*)(ho + (size_t)node * H + (j & 7) * 8) = v;
        }
    }
}

// ---------- pool (batch sorted -> range per graph) + head ----------
__global__ __launch_bounds__(192) void pool_head_kernel(
    const __hip_bfloat16* __restrict__ h1, const __hip_bfloat16* __restrict__ h2,
    const __hip_bfloat16* __restrict__ h3, const int* __restrict__ batch,
    const float* __restrict__ lin1_w, const float* __restrict__ lin1_b,
    const float* __restrict__ lin2_w, const float* __restrict__ lin2_b,
    float* __restrict__ out) {
    __shared__ float s_row[3 * H];
    __shared__ float s_mid[3 * H];
    __shared__ float s_z[C_CLS];
    __shared__ int s_se[2];

    int g = blockIdx.x;
    int j = threadIdx.x;
    if (j < 2) {
        int target = g + j;
        int lo = 0, hi = N_NODES;
        while (lo < hi) {
            int mid = (lo + hi) >> 1;
            if (batch[mid] < target) lo = mid + 1; else hi = mid;
        }
        s_se[j] = lo;
    }
    __syncthreads();
    int ns = s_se[0], ne = s_se[1];

    int which = j >> 6;
    int f = j & 63;
    const __hip_bfloat16* h = (which == 0) ? h1 : ((which == 1) ? h2 : h3);
    float p0 = 0.f, p1 = 0.f, p2 = 0.f, p3 = 0.f;
    int n = ns;
    for (; n + 3 < ne; n += 4) {
        p0 += __bfloat162float(h[(size_t)n * H + f]);
        p1 += __bfloat162float(h[(size_t)(n + 1) * H + f]);
        p2 += __bfloat162float(h[(size_t)(n + 2) * H + f]);
        p3 += __bfloat162float(h[(size_t)(n + 3) * H + f]);
    }
    for (; n < ne; n++) p0 += __bfloat162float(h[(size_t)n * H + f]);
    s_row[j] = (p0 + p1) + (p2 + p3);
    __syncthreads();

    float acc = lin1_b[j];
    for (int k = 0; k < 3 * H; k++) acc += s_row[k] * lin1_w[k * (3 * H) + j];
    s_mid[j] = fmaxf(acc, 0.f);
    __syncthreads();

    if (j < C_CLS) {
        float z = lin2_b[j];
        for (int k = 0; k < 3 * H; k++) z += s_mid[k] * lin2_w[k * C_CLS + j];
        s_z[j] = z;
    }
    __syncthreads();
    if (j < C_CLS) {
        float z0 = s_z[0], z1 = s_z[1];
        float mx = fmaxf(z0, z1);
        float lse = mx + logf(expf(z0 - mx) + expf(z1 - mx));
        out[g * C_CLS + j] = s_z[j];
        out[G_GRAPHS * C_CLS + g * C_CLS + j] = s_z[j] - lse;
    }
}

extern "C" void kernel_launch(void* const* d_in, const int* in_sizes, int n_in,
                              void* d_out, int out_size, void* d_ws, size_t ws_size,
                              hipStream_t stream) {
    const float* x = (const float*)d_in[0];
    const float* cw1[3], *cb1[3], *cg[3], *cbb[3], *cm[3], *cv[3], *cw2[3], *cb2[3];
    for (int l = 0; l < 3; l++) {
        int b = 1 + 8 * l;
        cw1[l] = (const float*)d_in[b + 0];
        cb1[l] = (const float*)d_in[b + 1];
        cg[l]  = (const float*)d_in[b + 2];
        cbb[l] = (const float*)d_in[b + 3];
        cm[l]  = (const float*)d_in[b + 4];
        cv[l]  = (const float*)d_in[b + 5];
        cw2[l] = (const float*)d_in[b + 6];
        cb2[l] = (const float*)d_in[b + 7];
    }
    const float* lin1_w = (const float*)d_in[25];
    const float* lin1_b = (const float*)d_in[26];
    const float* lin2_w = (const float*)d_in[27];
    const float* lin2_b = (const float*)d_in[28];
    const int* edge_index = (const int*)d_in[29];
    const int* batch = (const int*)d_in[30];
    const int* src = edge_index;
    const int* dst = edge_index + N_EDGES;
    float* out = (float*)d_out;

    // workspace layout
    int* edge_src = (int*)d_ws;                     // E
    int* gpacked = edge_src + N_EDGES;              // E
    int* gbh = gpacked + N_EDGES;                   // NBUCK
    int* bucket_start = gbh + NBUCK;                // NBUCK+1
    int* cursor = bucket_start + NBUCK + 1;         // NBUCK
    int* row_start = cursor + NBUCK;                // N+2
    uintptr_t hp = (uintptr_t)(row_start + N_NODES + 2);
    hp = (hp + 127) & ~(uintptr_t)127;
    unsigned short* wt = (unsigned short*)hp;       // 5 * H*H bf16
    uint2* xb = (uint2*)(wt + 5 * H * H);           // N
    __hip_bfloat16* h1 = (__hip_bfloat16*)(xb + N_NODES);  // N*H each
    __hip_bfloat16* h2 = h1 + (size_t)N_NODES * H;
    __hip_bfloat16* h3 = h2 + (size_t)N_NODES * H;

    const unsigned short* w2t_0 = wt + 0 * H * H;
    const unsigned short* w1t_1 = wt + 1 * H * H;
    const unsigned short* w2t_1 = wt + 2 * H * H;
    const unsigned short* w1t_2 = wt + 3 * H * H;
    const unsigned short* w2t_2 = wt + 4 * H * H;

    // ---- prep (weights transpose + x pack) + CSR build ----
    hipMemsetAsync(gbh, 0, NBUCK * sizeof(int), stream);
    prep_kernel<<<5 + (N_NODES + 255) / 256, 256, 0, stream>>>(
        cw2[0], cw1[1], cw2[1], cw1[2], cw2[2], wt, x, xb);
    bhist_kernel<<<CSR_BLOCKS, 256, 0, stream>>>(dst, gbh);
    bscan_kernel<<<1, 256, 0, stream>>>(gbh, bucket_start, cursor, row_start);
    bscatter_kernel<<<CSR_BLOCKS, 256, 0, stream>>>(src, dst, cursor, gpacked);
    bcsr_kernel<<<NBUCK, 256, 0, stream>>>(gpacked, bucket_start, row_start, edge_src);

    const int fgrid = (N_NODES + NPB - 1) / NPB;   // 391

    // ---- layer 1 ----
    gin1_fused_kernel<<<fgrid, 512, 0, stream>>>(x, xb, row_start, edge_src,
        cw1[0], cb1[0], cg[0], cbb[0], cm[0], cv[0], w2t_0, cb2[0], h1);
    // ---- layer 2 ----
    gin_fused_kernel<<<fgrid, 512, 0, stream>>>(h1, row_start, edge_src,
        w1t_1, cb1[1], cg[1], cbb[1], cm[1], cv[1], w2t_1, cb2[1], h2);
    // ---- layer 3 ----
    gin_fused_kernel<<<fgrid, 512, 0, stream>>>(h2, row_start, edge_src,
        w1t_2, cb1[2], cg[2], cbb[2], cm[2], cv[2], w2t_2, cb2[2], h3);
    // ---- pool + head ----
    pool_head_kernel<<<G_GRAPHS, 3 * H, 0, stream>>>(h1, h2, h3, batch,
        lin1_w, lin1_b, lin2_w, lin2_b, out);
}

// Round 14
// 308.537 us; speedup vs baseline: 1.1707x; 1.1707x over previous
//
#include <hip/hip_runtime.h>
#include <hip/hip_bf16.h>
#include <math.h>

#define N_NODES 50000
#define N_EDGES 1600000
#define H 64
#define G_GRAPHS 512
#define C_CLS 2
#define BN_EPS 1e-5f
#define NBUCK 196           // buckets of 256 nodes: dst>>8 in [0,196)
#define E4 (N_EDGES / 4)    // 400000
#define CSR_BLOCKS ((E4 + 511) / 512)   // 782, each handles 2048 edges

typedef __attribute__((ext_vector_type(8))) short short8;
typedef __attribute__((ext_vector_type(4))) float floatx4;

__device__ __forceinline__ float bflo(unsigned int u) { return __uint_as_float(u << 16); }
__device__ __forceinline__ float bfhi(unsigned int u) { return __uint_as_float(u & 0xffff0000u); }
__device__ __forceinline__ unsigned int bf16_rne(float f) {
    unsigned int u = __float_as_uint(f);
    u += 0x7fffu + ((u >> 16) & 1u);
    return u >> 16;
}

// ---------- CSR pass 1: global bucket histogram (LDS-privatized) ----------
__global__ __launch_bounds__(256) void bhist_kernel(const int* __restrict__ dst,
                                                    int* __restrict__ gbh) {
    __shared__ int bh[NBUCK];
    int t = threadIdx.x;
    if (t < NBUCK) bh[t] = 0;
    __syncthreads();
    int base = blockIdx.x * 512;
#pragma unroll
    for (int p = 0; p < 2; p++) {
        int i = base + p * 256 + t;
        if (i < E4) {
            int4 d = ((const int4*)dst)[i];
            atomicAdd(&bh[d.x >> 8], 1);
            atomicAdd(&bh[d.y >> 8], 1);
            atomicAdd(&bh[d.z >> 8], 1);
            atomicAdd(&bh[d.w >> 8], 1);
        }
    }
    __syncthreads();
    if (t < NBUCK && bh[t]) atomicAdd(&gbh[t], bh[t]);
}

// ---------- CSR pass 2: exclusive scan of 196 bucket counts ----------
__global__ __launch_bounds__(256) void bscan_kernel(const int* __restrict__ gbh,
                                                    int* __restrict__ bucket_start,
                                                    int* __restrict__ cursor,
                                                    int* __restrict__ row_start) {
    __shared__ int s[256];
    int t = threadIdx.x;
    int v = (t < NBUCK) ? gbh[t] : 0;
    s[t] = v;
    __syncthreads();
    for (int off = 1; off < 256; off <<= 1) {
        int u = 0;
        if (t >= off) u = s[t - off];
        __syncthreads();
        if (t >= off) s[t] += u;
        __syncthreads();
    }
    int excl = s[t] - v;
    if (t < NBUCK) { bucket_start[t] = excl; cursor[t] = excl; }
    if (t == 0) { bucket_start[NBUCK] = N_EDGES; row_start[N_NODES] = N_EDGES; }
}

// ---------- CSR pass 3: scatter edges into buckets (rank via LDS atomics) ----------
__global__ __launch_bounds__(256) void bscatter_kernel(const int* __restrict__ src,
                                                       const int* __restrict__ dst,
                                                       int* __restrict__ cursor,
                                                       int* __restrict__ gpacked) {
    __shared__ int bh[NBUCK];
    int t = threadIdx.x;
    if (t < NBUCK) bh[t] = 0;
    __syncthreads();
    int base = blockIdx.x * 512;

    int pkA[4], bkA[4], lrA[4]; bool vA = false;
    int pkB[4], bkB[4], lrB[4]; bool vB = false;
    {
        int i = base + t;
        if (i < E4) {
            vA = true;
            int4 s4 = ((const int4*)src)[i];
            int4 d4 = ((const int4*)dst)[i];
            bkA[0] = d4.x >> 8; pkA[0] = ((d4.x & 255) << 16) | s4.x; lrA[0] = atomicAdd(&bh[bkA[0]], 1);
            bkA[1] = d4.y >> 8; pkA[1] = ((d4.y & 255) << 16) | s4.y; lrA[1] = atomicAdd(&bh[bkA[1]], 1);
            bkA[2] = d4.z >> 8; pkA[2] = ((d4.z & 255) << 16) | s4.z; lrA[2] = atomicAdd(&bh[bkA[2]], 1);
            bkA[3] = d4.w >> 8; pkA[3] = ((d4.w & 255) << 16) | s4.w; lrA[3] = atomicAdd(&bh[bkA[3]], 1);
        }
    }
    {
        int i = base + 256 + t;
        if (i < E4) {
            vB = true;
            int4 s4 = ((const int4*)src)[i];
            int4 d4 = ((const int4*)dst)[i];
            bkB[0] = d4.x >> 8; pkB[0] = ((d4.x & 255) << 16) | s4.x; lrB[0] = atomicAdd(&bh[bkB[0]], 1);
            bkB[1] = d4.y >> 8; pkB[1] = ((d4.y & 255) << 16) | s4.y; lrB[1] = atomicAdd(&bh[bkB[1]], 1);
            bkB[2] = d4.z >> 8; pkB[2] = ((d4.z & 255) << 16) | s4.z; lrB[2] = atomicAdd(&bh[bkB[2]], 1);
            bkB[3] = d4.w >> 8; pkB[3] = ((d4.w & 255) << 16) | s4.w; lrB[3] = atomicAdd(&bh[bkB[3]], 1);
        }
    }
    __syncthreads();
    if (t < NBUCK) {
        int c = bh[t];
        bh[t] = c ? atomicAdd(&cursor[t], c) : 0;   // per-(block,bucket) base
    }
    __syncthreads();
    if (vA) {
#pragma unroll
        for (int q = 0; q < 4; q++) gpacked[bh[bkA[q]] + lrA[q]] = pkA[q];
    }
    if (vB) {
#pragma unroll
        for (int q = 0; q < 4; q++) gpacked[bh[bkB[q]] + lrB[q]] = pkB[q];
    }
}

// ---------- CSR pass 4: per-bucket local CSR (256 nodes/bucket) ----------
__global__ __launch_bounds__(256) void bcsr_kernel(const int* __restrict__ gpacked,
                                                   const int* __restrict__ bucket_start,
                                                   int* __restrict__ row_start,
                                                   int* __restrict__ edge_src) {
    __shared__ int cnt[256];
    __shared__ int pref[256];
    int b = blockIdx.x;
    int t = threadIdx.x;
    int bs = bucket_start[b], be = bucket_start[b + 1];
    cnt[t] = 0;
    __syncthreads();
    for (int i = bs + t; i < be; i += 256) atomicAdd(&cnt[gpacked[i] >> 16], 1);
    __syncthreads();
    int v = cnt[t];
    pref[t] = v;
    __syncthreads();
    for (int off = 1; off < 256; off <<= 1) {
        int u = 0;
        if (t >= off) u = pref[t - off];
        __syncthreads();
        if (t >= off) pref[t] += u;
        __syncthreads();
    }
    int excl = pref[t] - v;
    int node = b * 256 + t;
    if (node < N_NODES) row_start[node] = bs + excl;
    cnt[t] = excl;        // reuse as cursor
    __syncthreads();
    for (int i = bs + t; i < be; i += 256) {
        int p = gpacked[i];
        int pos = atomicAdd(&cnt[p >> 16], 1);
        edge_src[bs + pos] = p & 0xffff;
    }
}

// ---------- layer 1a: gather(din=3) + first linear + BN + relu, no LDS ----------
__global__ __launch_bounds__(512) void gather3_mid_kernel(
    const float* __restrict__ x, const int* __restrict__ row_start,
    const int* __restrict__ edge_src,
    const float* __restrict__ w1, const float* __restrict__ b1,
    const float* __restrict__ bn_g, const float* __restrict__ bn_b,
    const float* __restrict__ bn_m, const float* __restrict__ bn_v,
    __hip_bfloat16* __restrict__ mid) {
    int tid = threadIdx.x;
    int wave = tid >> 6;
    int j = tid & 63;
    int node = blockIdx.x * 8 + wave;   // grid exactly covers N

    int rs = row_start[node], re = row_start[node + 1];
    float a0 = 0.f, a1 = 0.f, a2 = 0.f;
    for (int t = rs + j; t < re; t += 64) {
        int s = edge_src[t];
        a0 += x[s * 3 + 0];
        a1 += x[s * 3 + 1];
        a2 += x[s * 3 + 2];
    }
#pragma unroll
    for (int off = 32; off > 0; off >>= 1) {
        a0 += __shfl_xor(a0, off);
        a1 += __shfl_xor(a1, off);
        a2 += __shfl_xor(a2, off);
    }
    float in0 = a0 + x[node * 3 + 0];
    float in1 = a1 + x[node * 3 + 1];
    float in2 = a2 + x[node * 3 + 2];

    float sc = rsqrtf(bn_v[j] + BN_EPS) * bn_g[j];
    float sh = bn_b[j] - bn_m[j] * sc;
    float m = b1[j] + in0 * w1[j] + in1 * w1[H + j] + in2 * w1[2 * H + j];
    m = fmaxf(m * sc + sh, 0.f);
    ((unsigned short*)mid)[(size_t)node * H + j] = (unsigned short)bf16_rne(m);
}

// ---------- layer 1b: h1 = relu(mid@w2 + b2) via MFMA ----------
#define IOP 72
__global__ __launch_bounds__(256) void matmul2_mfma_kernel(
    const __hip_bfloat16* __restrict__ xin,
    const float* __restrict__ w2, const float* __restrict__ b2,
    __hip_bfloat16* __restrict__ hout) {
    __shared__ unsigned short s_w2t[H * IOP];
    __shared__ unsigned short s_out[4][16 * IOP];

    int tid = threadIdx.x;
    for (int idx = tid; idx < H * H; idx += 256) {
        int k = idx >> 6, jj = idx & 63;
        s_w2t[jj * IOP + k] = (unsigned short)bf16_rne(w2[idx]);
    }
    int lane = tid & 63, wave = tid >> 6;
    int quad = lane >> 4, l15 = lane & 15;
    float bb2[4];
#pragma unroll
    for (int jt = 0; jt < 4; jt++) bb2[jt] = b2[jt * 16 + l15];
    __syncthreads();

    int base = blockIdx.x * 64 + wave * 16;
    const unsigned short* xr = (const unsigned short*)xin;
    int am = min(base + l15, N_NODES - 1);
    short8 a0 = *(const short8*)(xr + (size_t)am * H + quad * 8);
    short8 a1 = *(const short8*)(xr + (size_t)am * H + quad * 8 + 32);

    unsigned short* outw = s_out[wave];
#pragma unroll
    for (int jt = 0; jt < 4; jt++) {
        short8 b0 = *(const short8*)&s_w2t[(jt * 16 + l15) * IOP + quad * 8];
        short8 bv = *(const short8*)&s_w2t[(jt * 16 + l15) * IOP + quad * 8 + 32];
        floatx4 c = {0.f, 0.f, 0.f, 0.f};
        c = __builtin_amdgcn_mfma_f32_16x16x32_bf16(a0, b0, c, 0, 0, 0);
        c = __builtin_amdgcn_mfma_f32_16x16x32_bf16(a1, bv, c, 0, 0, 0);
#pragma unroll
        for (int r = 0; r < 4; r++) {
            float v = fmaxf(c[r] + bb2[jt], 0.f);
            outw[(quad * 4 + r) * IOP + jt * 16 + l15] = (unsigned short)bf16_rne(v);
        }
    }
    __syncthreads();

    unsigned short* ho = (unsigned short*)hout;
#pragma unroll
    for (int cc = 0; cc < 2; cc++) {
        int r = cc * 8 + (lane >> 3);
        int node = base + r;
        if (node < N_NODES) {
            short8 v = *(const short8*)&outw[r * IOP + (lane & 7) * 8];
            *(short8*)(ho + (size_t)node * H + (lane & 7) * 8) = v;
        }
    }
}

// ---------- pure gather: xs[n] = h[n] + sum_{j->n} h[j], dwordx4, 2x unroll ----------
// octet o = lane>>3 handles edges i+o and i+8+o; lane loads 2x 16B = two edges'
// 8-feature slices per iteration -> TWO independent loads in flight.
__global__ __launch_bounds__(512) void gather_kernel(
    const __hip_bfloat16* __restrict__ hin, const int* __restrict__ row_start,
    const int* __restrict__ edge_src, __hip_bfloat16* __restrict__ xs) {
    int tid = threadIdx.x;
    int wave = tid >> 6;
    int j = tid & 63;
    int o = j >> 3;    // 0..7: which edge of the group of 8
    int jo = j & 7;    // feature octet: features 8*jo .. 8*jo+7
    int node = blockIdx.x * 8 + wave;   // grid exactly covers N

    const char* hb = (const char*)hin;
    int rs = row_start[node], re = row_start[node + 1];
    float a0 = 0.f, a1 = 0.f, a2 = 0.f, a3 = 0.f, a4 = 0.f, a5 = 0.f, a6 = 0.f, a7 = 0.f;
    float b0 = 0.f, b1 = 0.f, b2 = 0.f, b3 = 0.f, b4 = 0.f, b5 = 0.f, b6 = 0.f, b7 = 0.f;
    for (int base = rs; base < re; base += 64) {
        int idx = base + j;
        int sv = (idx < re) ? edge_src[idx] : 0;
        int cnt = min(64, re - base);
        int i = 0;
        for (; i + 16 <= cnt; i += 16) {      // 16 edges/iter, 2 loads in flight
            int s0 = __shfl(sv, i + o);
            int s1 = __shfl(sv, i + 8 + o);
            uint4 r0 = *(const uint4*)(hb + (size_t)s0 * 128 + jo * 16);
            uint4 r1 = *(const uint4*)(hb + (size_t)s1 * 128 + jo * 16);
            a0 += bflo(r0.x); a1 += bfhi(r0.x);
            a2 += bflo(r0.y); a3 += bfhi(r0.y);
            a4 += bflo(r0.z); a5 += bfhi(r0.z);
            a6 += bflo(r0.w); a7 += bfhi(r0.w);
            b0 += bflo(r1.x); b1 += bfhi(r1.x);
            b2 += bflo(r1.y); b3 += bfhi(r1.y);
            b4 += bflo(r1.z); b5 += bfhi(r1.z);
            b6 += bflo(r1.w); b7 += bfhi(r1.w);
        }
        for (; i + 8 <= cnt; i += 8) {        // leftover full octet
            int s = __shfl(sv, i + o);
            uint4 raw = *(const uint4*)(hb + (size_t)s * 128 + jo * 16);
            a0 += bflo(raw.x); a1 += bfhi(raw.x);
            a2 += bflo(raw.y); a3 += bfhi(raw.y);
            a4 += bflo(raw.z); a5 += bfhi(raw.z);
            a6 += bflo(raw.w); a7 += bfhi(raw.w);
        }
        if (i < cnt) {                        // tail: 1-7 edges
            int r = cnt - i;
            int s = __shfl(sv, i + (o < r ? o : 0));
            uint4 raw = *(const uint4*)(hb + (size_t)s * 128 + jo * 16);
            if (o < r) {
                a0 += bflo(raw.x); a1 += bfhi(raw.x);
                a2 += bflo(raw.y); a3 += bfhi(raw.y);
                a4 += bflo(raw.z); a5 += bfhi(raw.z);
                a6 += bflo(raw.w); a7 += bfhi(raw.w);
            }
        }
    }
    a0 += b0; a1 += b1; a2 += b2; a3 += b3;
    a4 += b4; a5 += b5; a6 += b6; a7 += b7;
    a0 += __shfl_xor(a0, 8); a0 += __shfl_xor(a0, 16); a0 += __shfl_xor(a0, 32);
    a1 += __shfl_xor(a1, 8); a1 += __shfl_xor(a1, 16); a1 += __shfl_xor(a1, 32);
    a2 += __shfl_xor(a2, 8); a2 += __shfl_xor(a2, 16); a2 += __shfl_xor(a2, 32);
    a3 += __shfl_xor(a3, 8); a3 += __shfl_xor(a3, 16); a3 += __shfl_xor(a3, 32);
    a4 += __shfl_xor(a4, 8); a4 += __shfl_xor(a4, 16); a4 += __shfl_xor(a4, 32);
    a5 += __shfl_xor(a5, 8); a5 += __shfl_xor(a5, 16); a5 += __shfl_xor(a5, 32);
    a6 += __shfl_xor(a6, 8); a6 += __shfl_xor(a6, 16); a6 += __shfl_xor(a6, 32);
    a7 += __shfl_xor(a7, 8); a7 += __shfl_xor(a7, 16); a7 += __shfl_xor(a7, 32);
    if (o == 0) {
        uint4 raw = *(const uint4*)(hb + (size_t)node * 128 + jo * 16);
        a0 += bflo(raw.x); a1 += bfhi(raw.x);
        a2 += bflo(raw.y); a3 += bfhi(raw.y);
        a4 += bflo(raw.z); a5 += bfhi(raw.z);
        a6 += bflo(raw.w); a7 += bfhi(raw.w);
        uint4 ov;
        ov.x = bf16_rne(a0) | (bf16_rne(a1) << 16);
        ov.y = bf16_rne(a2) | (bf16_rne(a3) << 16);
        ov.z = bf16_rne(a4) | (bf16_rne(a5) << 16);
        ov.w = bf16_rne(a6) | (bf16_rne(a7) << 16);
        *(uint4*)((char*)xs + (size_t)node * 128 + jo * 16) = ov;
    }
}

// ---------- batched MFMA MLP: hout = relu(relu_bn(xs@w1+b1)@w2+b2) ----------
__global__ __launch_bounds__(256) void mlp_mfma_kernel(
    const __hip_bfloat16* __restrict__ xs,
    const float* __restrict__ w1, const float* __restrict__ b1,
    const float* __restrict__ bn_g, const float* __restrict__ bn_b,
    const float* __restrict__ bn_m, const float* __restrict__ bn_v,
    const float* __restrict__ w2, const float* __restrict__ b2,
    __hip_bfloat16* __restrict__ hout) {
    __shared__ unsigned short s_w1t[H * IOP];
    __shared__ unsigned short s_w2t[H * IOP];
    __shared__ unsigned short s_mid[4][16 * IOP];
    __shared__ unsigned short s_out[4][16 * IOP];

    int tid = threadIdx.x;
    for (int idx = tid; idx < H * H; idx += 256) {
        int k = idx >> 6, jj = idx & 63;
        s_w1t[jj * IOP + k] = (unsigned short)bf16_rne(w1[idx]);
        s_w2t[jj * IOP + k] = (unsigned short)bf16_rne(w2[idx]);
    }
    int lane = tid & 63, wave = tid >> 6;
    int quad = lane >> 4, l15 = lane & 15;
    float scl[4], sht[4], bb1[4], bb2[4];
#pragma unroll
    for (int jt = 0; jt < 4; jt++) {
        int j = jt * 16 + l15;
        float sc = rsqrtf(bn_v[j] + BN_EPS) * bn_g[j];
        scl[jt] = sc;
        sht[jt] = bn_b[j] - bn_m[j] * sc;
        bb1[jt] = b1[j];
        bb2[jt] = b2[j];
    }
    __syncthreads();

    int base = blockIdx.x * 64 + wave * 16;
    const unsigned short* xr = (const unsigned short*)xs;
    int am = min(base + l15, N_NODES - 1);
    short8 a0 = *(const short8*)(xr + (size_t)am * H + quad * 8);
    short8 a1 = *(const short8*)(xr + (size_t)am * H + quad * 8 + 32);

    unsigned short* mid = s_mid[wave];
    unsigned short* outw = s_out[wave];

#pragma unroll
    for (int jt = 0; jt < 4; jt++) {
        short8 b0 = *(const short8*)&s_w1t[(jt * 16 + l15) * IOP + quad * 8];
        short8 bv = *(const short8*)&s_w1t[(jt * 16 + l15) * IOP + quad * 8 + 32];
        floatx4 c = {0.f, 0.f, 0.f, 0.f};
        c = __builtin_amdgcn_mfma_f32_16x16x32_bf16(a0, b0, c, 0, 0, 0);
        c = __builtin_amdgcn_mfma_f32_16x16x32_bf16(a1, bv, c, 0, 0, 0);
#pragma unroll
        for (int r = 0; r < 4; r++) {
            float v = (c[r] + bb1[jt]) * scl[jt] + sht[jt];
            v = fmaxf(v, 0.f);
            mid[(quad * 4 + r) * IOP + jt * 16 + l15] = (unsigned short)bf16_rne(v);
        }
    }
    __syncthreads();

    short8 m0 = *(const short8*)&mid[l15 * IOP + quad * 8];
    short8 m1 = *(const short8*)&mid[l15 * IOP + quad * 8 + 32];
#pragma unroll
    for (int jt = 0; jt < 4; jt++) {
        short8 b0 = *(const short8*)&s_w2t[(jt * 16 + l15) * IOP + quad * 8];
        short8 bv = *(const short8*)&s_w2t[(jt * 16 + l15) * IOP + quad * 8 + 32];
        floatx4 c = {0.f, 0.f, 0.f, 0.f};
        c = __builtin_amdgcn_mfma_f32_16x16x32_bf16(m0, b0, c, 0, 0, 0);
        c = __builtin_amdgcn_mfma_f32_16x16x32_bf16(m1, bv, c, 0, 0, 0);
#pragma unroll
        for (int r = 0; r < 4; r++) {
            float v = fmaxf(c[r] + bb2[jt], 0.f);
            outw[(quad * 4 + r) * IOP + jt * 16 + l15] = (unsigned short)bf16_rne(v);
        }
    }
    __syncthreads();

    unsigned short* ho = (unsigned short*)hout;
#pragma unroll
    for (int cc = 0; cc < 2; cc++) {
        int r = cc * 8 + (lane >> 3);
        int node = base + r;
        if (node < N_NODES) {
            short8 v = *(const short8*)&outw[r * IOP + (lane & 7) * 8];
            *(short8*)(ho + (size_t)node * H + (lane & 7) * 8) = v;
        }
    }
}

// ---------- pool (batch sorted -> range per graph) + head ----------
__global__ __launch_bounds__(192) void pool_head_kernel(
    const __hip_bfloat16* __restrict__ h1, const __hip_bfloat16* __restrict__ h2,
    const __hip_bfloat16* __restrict__ h3, const int* __restrict__ batch,
    const float* __restrict__ lin1_w, const float* __restrict__ lin1_b,
    const float* __restrict__ lin2_w, const float* __restrict__ lin2_b,
    float* __restrict__ out) {
    __shared__ float s_row[3 * H];
    __shared__ float s_mid[3 * H];
    __shared__ float s_z[C_CLS];
    __shared__ int s_se[2];

    int g = blockIdx.x;
    int j = threadIdx.x;
    if (j < 2) {
        int target = g + j;
        int lo = 0, hi = N_NODES;
        while (lo < hi) {
            int mid = (lo + hi) >> 1;
            if (batch[mid] < target) lo = mid + 1; else hi = mid;
        }
        s_se[j] = lo;
    }
    __syncthreads();
    int ns = s_se[0], ne = s_se[1];

    int which = j >> 6;
    int f = j & 63;
    const __hip_bfloat16* h = (which == 0) ? h1 : ((which == 1) ? h2 : h3);
    float p0 = 0.f, p1 = 0.f, p2 = 0.f, p3 = 0.f;
    int n = ns;
    for (; n + 3 < ne; n += 4) {
        p0 += __bfloat162float(h[(size_t)n * H + f]);
        p1 += __bfloat162float(h[(size_t)(n + 1) * H + f]);
        p2 += __bfloat162float(h[(size_t)(n + 2) * H + f]);
        p3 += __bfloat162float(h[(size_t)(n + 3) * H + f]);
    }
    for (; n < ne; n++) p0 += __bfloat162float(h[(size_t)n * H + f]);
    s_row[j] = (p0 + p1) + (p2 + p3);
    __syncthreads();

    float acc = lin1_b[j];
    for (int k = 0; k < 3 * H; k++) acc += s_row[k] * lin1_w[k * (3 * H) + j];
    s_mid[j] = fmaxf(acc, 0.f);
    __syncthreads();

    if (j < C_CLS) {
        float z = lin2_b[j];
        for (int k = 0; k < 3 * H; k++) z += s_mid[k] * lin2_w[k * C_CLS + j];
        s_z[j] = z;
    }
    __syncthreads();
    if (j < C_CLS) {
        float z0 = s_z[0], z1 = s_z[1];
        float mx = fmaxf(z0, z1);
        float lse = mx + logf(expf(z0 - mx) + expf(z1 - mx));
        out[g * C_CLS + j] = s_z[j];
        out[G_GRAPHS * C_CLS + g * C_CLS + j] = s_z[j] - lse;
    }
}

extern "C" void kernel_launch(void* const* d_in, const int* in_sizes, int n_in,
                              void* d_out, int out_size, void* d_ws, size_t ws_size,
                              hipStream_t stream) {
    const float* x = (const float*)d_in[0];
    const float* cw1[3], *cb1[3], *cg[3], *cbb[3], *cm[3], *cv[3], *cw2[3], *cb2[3];
    for (int l = 0; l < 3; l++) {
        int b = 1 + 8 * l;
        cw1[l] = (const float*)d_in[b + 0];
        cb1[l] = (const float*)d_in[b + 1];
        cg[l]  = (const float*)d_in[b + 2];
        cbb[l] = (const float*)d_in[b + 3];
        cm[l]  = (const float*)d_in[b + 4];
        cv[l]  = (const float*)d_in[b + 5];
        cw2[l] = (const float*)d_in[b + 6];
        cb2[l] = (const float*)d_in[b + 7];
    }
    const float* lin1_w = (const float*)d_in[25];
    const float* lin1_b = (const float*)d_in[26];
    const float* lin2_w = (const float*)d_in[27];
    const float* lin2_b = (const float*)d_in[28];
    const int* edge_index = (const int*)d_in[29];
    const int* batch = (const int*)d_in[30];
    const int* src = edge_index;
    const int* dst = edge_index + N_EDGES;
    float* out = (float*)d_out;

    // workspace layout
    int* edge_src = (int*)d_ws;                     // E
    int* gpacked = edge_src + N_EDGES;              // E
    int* gbh = gpacked + N_EDGES;                   // NBUCK
    int* bucket_start = gbh + NBUCK;                // NBUCK+1
    int* cursor = bucket_start + NBUCK + 1;         // NBUCK
    int* row_start = cursor + NBUCK;                // N+2
    uintptr_t hp = (uintptr_t)(row_start + N_NODES + 2);
    hp = (hp + 127) & ~(uintptr_t)127;
    __hip_bfloat16* h1 = (__hip_bfloat16*)hp;       // N*H each
    __hip_bfloat16* h2 = h1 + (size_t)N_NODES * H;
    __hip_bfloat16* h3 = h2 + (size_t)N_NODES * H;
    __hip_bfloat16* xs = h3 + (size_t)N_NODES * H;

    // ---- build CSR via 2-digit radix (LDS atomics, ~150k global atomics) ----
    hipMemsetAsync(gbh, 0, NBUCK * sizeof(int), stream);
    bhist_kernel<<<CSR_BLOCKS, 256, 0, stream>>>(dst, gbh);
    bscan_kernel<<<1, 256, 0, stream>>>(gbh, bucket_start, cursor, row_start);
    bscatter_kernel<<<CSR_BLOCKS, 256, 0, stream>>>(src, dst, cursor, gpacked);
    bcsr_kernel<<<NBUCK, 256, 0, stream>>>(gpacked, bucket_start, row_start, edge_src);

    const int mlp_grid = (N_NODES + 63) / 64;   // 782

    // ---- layer 1 ----
    gather3_mid_kernel<<<N_NODES / 8, 512, 0, stream>>>(x, row_start, edge_src,
        cw1[0], cb1[0], cg[0], cbb[0], cm[0], cv[0], xs);
    matmul2_mfma_kernel<<<mlp_grid, 256, 0, stream>>>(xs, cw2[0], cb2[0], h1);
    // ---- layer 2 ----
    gather_kernel<<<N_NODES / 8, 512, 0, stream>>>(h1, row_start, edge_src, xs);
    mlp_mfma_kernel<<<mlp_grid, 256, 0, stream>>>(xs,
        cw1[1], cb1[1], cg[1], cbb[1], cm[1], cv[1], cw2[1], cb2[1], h2);
    // ---- layer 3 ----
    gather_kernel<<<N_NODES / 8, 512, 0, stream>>>(h2, row_start, edge_src, xs);
    mlp_mfma_kernel<<<mlp_grid, 256, 0, stream>>>(xs,
        cw1[2], cb1[2], cg[2], cbb[2], cm[2], cv[2], cw2[2], cb2[2], h3);
    // ---- pool + head ----
    pool_head_kernel<<<G_GRAPHS, 3 * H, 0, stream>>>(h1, h2, h3, batch,
        lin1_w, lin1_b, lin2_w, lin2_b, out);
}

// Round 15
// 283.972 us; speedup vs baseline: 1.2720x; 1.0865x over previous
//
#include <hip/hip_runtime.h>
#include <hip/hip_bf16.h>
#include <math.h>

#define N_NODES 50000
#define N_EDGES 1600000
#define H 64
#define G_GRAPHS 512
#define C_CLS 2
#define BN_EPS 1e-5f
#define NBUCK 196           // buckets of 256 nodes: dst>>8 in [0,196)
#define BUCKCAP 16384       // fixed bucket capacity (mean 8192, sigma~90 -> 90 sigma headroom)
#define E4 (N_EDGES / 4)    // 400000
#define CSR_BLOCKS ((E4 + 511) / 512)   // 782, each handles 2048 edges

typedef __attribute__((ext_vector_type(8))) short short8;
typedef __attribute__((ext_vector_type(4))) float floatx4;

__device__ __forceinline__ float bflo(unsigned int u) { return __uint_as_float(u << 16); }
__device__ __forceinline__ float bfhi(unsigned int u) { return __uint_as_float(u & 0xffff0000u); }
__device__ __forceinline__ unsigned int bf16_rne(float f) {
    unsigned int u = __float_as_uint(f);
    u += 0x7fffu + ((u >> 16) & 1u);
    return u >> 16;
}

// ---------- CSR pass 1 (single pass): scatter edges into fixed-cap buckets ----------
// rank within block via LDS atomics; one returning global atomic per (block,bucket).
__global__ __launch_bounds__(256) void scatter1_kernel(const int* __restrict__ src,
                                                       const int* __restrict__ dst,
                                                       int* __restrict__ gcnt,
                                                       int* __restrict__ gpacked) {
    __shared__ int bh[NBUCK];
    int t = threadIdx.x;
    if (t < NBUCK) bh[t] = 0;
    __syncthreads();
    int base = blockIdx.x * 512;

    int pkA[4], bkA[4], lrA[4]; bool vA = false;
    int pkB[4], bkB[4], lrB[4]; bool vB = false;
    {
        int i = base + t;
        if (i < E4) {
            vA = true;
            int4 s4 = ((const int4*)src)[i];
            int4 d4 = ((const int4*)dst)[i];
            bkA[0] = d4.x >> 8; pkA[0] = ((d4.x & 255) << 16) | s4.x; lrA[0] = atomicAdd(&bh[bkA[0]], 1);
            bkA[1] = d4.y >> 8; pkA[1] = ((d4.y & 255) << 16) | s4.y; lrA[1] = atomicAdd(&bh[bkA[1]], 1);
            bkA[2] = d4.z >> 8; pkA[2] = ((d4.z & 255) << 16) | s4.z; lrA[2] = atomicAdd(&bh[bkA[2]], 1);
            bkA[3] = d4.w >> 8; pkA[3] = ((d4.w & 255) << 16) | s4.w; lrA[3] = atomicAdd(&bh[bkA[3]], 1);
        }
    }
    {
        int i = base + 256 + t;
        if (i < E4) {
            vB = true;
            int4 s4 = ((const int4*)src)[i];
            int4 d4 = ((const int4*)dst)[i];
            bkB[0] = d4.x >> 8; pkB[0] = ((d4.x & 255) << 16) | s4.x; lrB[0] = atomicAdd(&bh[bkB[0]], 1);
            bkB[1] = d4.y >> 8; pkB[1] = ((d4.y & 255) << 16) | s4.y; lrB[1] = atomicAdd(&bh[bkB[1]], 1);
            bkB[2] = d4.z >> 8; pkB[2] = ((d4.z & 255) << 16) | s4.z; lrB[2] = atomicAdd(&bh[bkB[2]], 1);
            bkB[3] = d4.w >> 8; pkB[3] = ((d4.w & 255) << 16) | s4.w; lrB[3] = atomicAdd(&bh[bkB[3]], 1);
        }
    }
    __syncthreads();
    if (t < NBUCK) {
        int c = bh[t];
        bh[t] = c ? atomicAdd(&gcnt[t], c) : 0;   // per-(block,bucket) base within bucket
    }
    __syncthreads();
    if (vA) {
#pragma unroll
        for (int q = 0; q < 4; q++) gpacked[bkA[q] * BUCKCAP + bh[bkA[q]] + lrA[q]] = pkA[q];
    }
    if (vB) {
#pragma unroll
        for (int q = 0; q < 4; q++) gpacked[bkB[q] * BUCKCAP + bh[bkB[q]] + lrB[q]] = pkB[q];
    }
}

// ---------- CSR pass 2: per-bucket local CSR; bucket offset computed in-block ----------
__global__ __launch_bounds__(256) void bcsr_kernel(const int* __restrict__ gpacked,
                                                   const int* __restrict__ gcnt,
                                                   int* __restrict__ row_start,
                                                   int* __restrict__ edge_src) {
    __shared__ int cnt[256];
    __shared__ int pref[256];
    int b = blockIdx.x;
    int t = threadIdx.x;

    // compute bucket_start[b] = exclusive prefix of gcnt over buckets < b
    int v = (t < NBUCK) ? gcnt[t] : 0;
    pref[t] = v;
    __syncthreads();
    for (int off = 1; off < 256; off <<= 1) {
        int u = 0;
        if (t >= off) u = pref[t - off];
        __syncthreads();
        if (t >= off) pref[t] += u;
        __syncthreads();
    }
    int bs = (b > 0) ? pref[b - 1] : 0;     // exclusive prefix at b
    int cnt_b = gcnt[b];
    if (b == 0 && t == 0) row_start[N_NODES] = N_EDGES;
    __syncthreads();

    const int* gp = gpacked + (size_t)b * BUCKCAP;
    cnt[t] = 0;
    __syncthreads();
    for (int i = t; i < cnt_b; i += 256) atomicAdd(&cnt[gp[i] >> 16], 1);
    __syncthreads();
    int c = cnt[t];
    pref[t] = c;
    __syncthreads();
    for (int off = 1; off < 256; off <<= 1) {
        int u = 0;
        if (t >= off) u = pref[t - off];
        __syncthreads();
        if (t >= off) pref[t] += u;
        __syncthreads();
    }
    int excl = pref[t] - c;
    int node = b * 256 + t;
    if (node < N_NODES) row_start[node] = bs + excl;
    cnt[t] = excl;        // reuse as cursor
    __syncthreads();
    for (int i = t; i < cnt_b; i += 256) {
        int p = gp[i];
        int pos = atomicAdd(&cnt[p >> 16], 1);
        edge_src[bs + pos] = p & 0xffff;
    }
}

// ---------- layer 1a: gather(din=3) + first linear + BN + relu, no LDS ----------
__global__ __launch_bounds__(512) void gather3_mid_kernel(
    const float* __restrict__ x, const int* __restrict__ row_start,
    const int* __restrict__ edge_src,
    const float* __restrict__ w1, const float* __restrict__ b1,
    const float* __restrict__ bn_g, const float* __restrict__ bn_b,
    const float* __restrict__ bn_m, const float* __restrict__ bn_v,
    __hip_bfloat16* __restrict__ mid) {
    int tid = threadIdx.x;
    int wave = tid >> 6;
    int j = tid & 63;
    int node = blockIdx.x * 8 + wave;   // grid exactly covers N

    int rs = row_start[node], re = row_start[node + 1];
    float a0 = 0.f, a1 = 0.f, a2 = 0.f;
    for (int t = rs + j; t < re; t += 64) {
        int s = edge_src[t];
        a0 += x[s * 3 + 0];
        a1 += x[s * 3 + 1];
        a2 += x[s * 3 + 2];
    }
#pragma unroll
    for (int off = 32; off > 0; off >>= 1) {
        a0 += __shfl_xor(a0, off);
        a1 += __shfl_xor(a1, off);
        a2 += __shfl_xor(a2, off);
    }
    float in0 = a0 + x[node * 3 + 0];
    float in1 = a1 + x[node * 3 + 1];
    float in2 = a2 + x[node * 3 + 2];

    float sc = rsqrtf(bn_v[j] + BN_EPS) * bn_g[j];
    float sh = bn_b[j] - bn_m[j] * sc;
    float m = b1[j] + in0 * w1[j] + in1 * w1[H + j] + in2 * w1[2 * H + j];
    m = fmaxf(m * sc + sh, 0.f);
    ((unsigned short*)mid)[(size_t)node * H + j] = (unsigned short)bf16_rne(m);
}

// ---------- layer 1b: h1 = relu(mid@w2 + b2) via MFMA ----------
#define IOP 72
__global__ __launch_bounds__(256) void matmul2_mfma_kernel(
    const __hip_bfloat16* __restrict__ xin,
    const float* __restrict__ w2, const float* __restrict__ b2,
    __hip_bfloat16* __restrict__ hout) {
    __shared__ unsigned short s_w2t[H * IOP];
    __shared__ unsigned short s_out[4][16 * IOP];

    int tid = threadIdx.x;
    for (int idx = tid; idx < H * H; idx += 256) {
        int k = idx >> 6, jj = idx & 63;
        s_w2t[jj * IOP + k] = (unsigned short)bf16_rne(w2[idx]);
    }
    int lane = tid & 63, wave = tid >> 6;
    int quad = lane >> 4, l15 = lane & 15;
    float bb2[4];
#pragma unroll
    for (int jt = 0; jt < 4; jt++) bb2[jt] = b2[jt * 16 + l15];
    __syncthreads();

    int base = blockIdx.x * 64 + wave * 16;
    const unsigned short* xr = (const unsigned short*)xin;
    int am = min(base + l15, N_NODES - 1);
    short8 a0 = *(const short8*)(xr + (size_t)am * H + quad * 8);
    short8 a1 = *(const short8*)(xr + (size_t)am * H + quad * 8 + 32);

    unsigned short* outw = s_out[wave];
#pragma unroll
    for (int jt = 0; jt < 4; jt++) {
        short8 b0 = *(const short8*)&s_w2t[(jt * 16 + l15) * IOP + quad * 8];
        short8 bv = *(const short8*)&s_w2t[(jt * 16 + l15) * IOP + quad * 8 + 32];
        floatx4 c = {0.f, 0.f, 0.f, 0.f};
        c = __builtin_amdgcn_mfma_f32_16x16x32_bf16(a0, b0, c, 0, 0, 0);
        c = __builtin_amdgcn_mfma_f32_16x16x32_bf16(a1, bv, c, 0, 0, 0);
#pragma unroll
        for (int r = 0; r < 4; r++) {
            float v = fmaxf(c[r] + bb2[jt], 0.f);
            outw[(quad * 4 + r) * IOP + jt * 16 + l15] = (unsigned short)bf16_rne(v);
        }
    }
    __syncthreads();

    unsigned short* ho = (unsigned short*)hout;
#pragma unroll
    for (int cc = 0; cc < 2; cc++) {
        int r = cc * 8 + (lane >> 3);
        int node = base + r;
        if (node < N_NODES) {
            short8 v = *(const short8*)&outw[r * IOP + (lane & 7) * 8];
            *(short8*)(ho + (size_t)node * H + (lane & 7) * 8) = v;
        }
    }
}

// ---------- pure gather: xs[n] = h[n] + sum_{j->n} h[j], dwordx4, 2x unroll ----------
__global__ __launch_bounds__(512) void gather_kernel(
    const __hip_bfloat16* __restrict__ hin, const int* __restrict__ row_start,
    const int* __restrict__ edge_src, __hip_bfloat16* __restrict__ xs) {
    int tid = threadIdx.x;
    int wave = tid >> 6;
    int j = tid & 63;
    int o = j >> 3;    // 0..7: which edge of the group of 8
    int jo = j & 7;    // feature octet: features 8*jo .. 8*jo+7
    int node = blockIdx.x * 8 + wave;   // grid exactly covers N

    const char* hb = (const char*)hin;
    int rs = row_start[node], re = row_start[node + 1];
    float a0 = 0.f, a1 = 0.f, a2 = 0.f, a3 = 0.f, a4 = 0.f, a5 = 0.f, a6 = 0.f, a7 = 0.f;
    float b0 = 0.f, b1 = 0.f, b2 = 0.f, b3 = 0.f, b4 = 0.f, b5 = 0.f, b6 = 0.f, b7 = 0.f;
    for (int base = rs; base < re; base += 64) {
        int idx = base + j;
        int sv = (idx < re) ? edge_src[idx] : 0;
        int cnt = min(64, re - base);
        int i = 0;
        for (; i + 16 <= cnt; i += 16) {      // 16 edges/iter, 2 loads in flight
            int s0 = __shfl(sv, i + o);
            int s1 = __shfl(sv, i + 8 + o);
            uint4 r0 = *(const uint4*)(hb + (size_t)s0 * 128 + jo * 16);
            uint4 r1 = *(const uint4*)(hb + (size_t)s1 * 128 + jo * 16);
            a0 += bflo(r0.x); a1 += bfhi(r0.x);
            a2 += bflo(r0.y); a3 += bfhi(r0.y);
            a4 += bflo(r0.z); a5 += bfhi(r0.z);
            a6 += bflo(r0.w); a7 += bfhi(r0.w);
            b0 += bflo(r1.x); b1 += bfhi(r1.x);
            b2 += bflo(r1.y); b3 += bfhi(r1.y);
            b4 += bflo(r1.z); b5 += bfhi(r1.z);
            b6 += bflo(r1.w); b7 += bfhi(r1.w);
        }
        for (; i + 8 <= cnt; i += 8) {        // leftover full octet
            int s = __shfl(sv, i + o);
            uint4 raw = *(const uint4*)(hb + (size_t)s * 128 + jo * 16);
            a0 += bflo(raw.x); a1 += bfhi(raw.x);
            a2 += bflo(raw.y); a3 += bfhi(raw.y);
            a4 += bflo(raw.z); a5 += bfhi(raw.z);
            a6 += bflo(raw.w); a7 += bfhi(raw.w);
        }
        if (i < cnt) {                        // tail: 1-7 edges
            int r = cnt - i;
            int s = __shfl(sv, i + (o < r ? o : 0));
            uint4 raw = *(const uint4*)(hb + (size_t)s * 128 + jo * 16);
            if (o < r) {
                a0 += bflo(raw.x); a1 += bfhi(raw.x);
                a2 += bflo(raw.y); a3 += bfhi(raw.y);
                a4 += bflo(raw.z); a5 += bfhi(raw.z);
                a6 += bflo(raw.w); a7 += bfhi(raw.w);
            }
        }
    }
    a0 += b0; a1 += b1; a2 += b2; a3 += b3;
    a4 += b4; a5 += b5; a6 += b6; a7 += b7;
    a0 += __shfl_xor(a0, 8); a0 += __shfl_xor(a0, 16); a0 += __shfl_xor(a0, 32);
    a1 += __shfl_xor(a1, 8); a1 += __shfl_xor(a1, 16); a1 += __shfl_xor(a1, 32);
    a2 += __shfl_xor(a2, 8); a2 += __shfl_xor(a2, 16); a2 += __shfl_xor(a2, 32);
    a3 += __shfl_xor(a3, 8); a3 += __shfl_xor(a3, 16); a3 += __shfl_xor(a3, 32);
    a4 += __shfl_xor(a4, 8); a4 += __shfl_xor(a4, 16); a4 += __shfl_xor(a4, 32);
    a5 += __shfl_xor(a5, 8); a5 += __shfl_xor(a5, 16); a5 += __shfl_xor(a5, 32);
    a6 += __shfl_xor(a6, 8); a6 += __shfl_xor(a6, 16); a6 += __shfl_xor(a6, 32);
    a7 += __shfl_xor(a7, 8); a7 += __shfl_xor(a7, 16); a7 += __shfl_xor(a7, 32);
    if (o == 0) {
        uint4 raw = *(const uint4*)(hb + (size_t)node * 128 + jo * 16);
        a0 += bflo(raw.x); a1 += bfhi(raw.x);
        a2 += bflo(raw.y); a3 += bfhi(raw.y);
        a4 += bflo(raw.z); a5 += bfhi(raw.z);
        a6 += bflo(raw.w); a7 += bfhi(raw.w);
        uint4 ov;
        ov.x = bf16_rne(a0) | (bf16_rne(a1) << 16);
        ov.y = bf16_rne(a2) | (bf16_rne(a3) << 16);
        ov.z = bf16_rne(a4) | (bf16_rne(a5) << 16);
        ov.w = bf16_rne(a6) | (bf16_rne(a7) << 16);
        *(uint4*)((char*)xs + (size_t)node * 128 + jo * 16) = ov;
    }
}

// ---------- batched MFMA MLP: hout = relu(relu_bn(xs@w1+b1)@w2+b2) ----------
__global__ __launch_bounds__(256) void mlp_mfma_kernel(
    const __hip_bfloat16* __restrict__ xs,
    const float* __restrict__ w1, const float* __restrict__ b1,
    const float* __restrict__ bn_g, const float* __restrict__ bn_b,
    const float* __restrict__ bn_m, const float* __restrict__ bn_v,
    const float* __restrict__ w2, const float* __restrict__ b2,
    __hip_bfloat16* __restrict__ hout) {
    __shared__ unsigned short s_w1t[H * IOP];
    __shared__ unsigned short s_w2t[H * IOP];
    __shared__ unsigned short s_mid[4][16 * IOP];
    __shared__ unsigned short s_out[4][16 * IOP];

    int tid = threadIdx.x;
    for (int idx = tid; idx < H * H; idx += 256) {
        int k = idx >> 6, jj = idx & 63;
        s_w1t[jj * IOP + k] = (unsigned short)bf16_rne(w1[idx]);
        s_w2t[jj * IOP + k] = (unsigned short)bf16_rne(w2[idx]);
    }
    int lane = tid & 63, wave = tid >> 6;
    int quad = lane >> 4, l15 = lane & 15;
    float scl[4], sht[4], bb1[4], bb2[4];
#pragma unroll
    for (int jt = 0; jt < 4; jt++) {
        int j = jt * 16 + l15;
        float sc = rsqrtf(bn_v[j] + BN_EPS) * bn_g[j];
        scl[jt] = sc;
        sht[jt] = bn_b[j] - bn_m[j] * sc;
        bb1[jt] = b1[j];
        bb2[jt] = b2[j];
    }
    __syncthreads();

    int base = blockIdx.x * 64 + wave * 16;
    const unsigned short* xr = (const unsigned short*)xs;
    int am = min(base + l15, N_NODES - 1);
    short8 a0 = *(const short8*)(xr + (size_t)am * H + quad * 8);
    short8 a1 = *(const short8*)(xr + (size_t)am * H + quad * 8 + 32);

    unsigned short* mid = s_mid[wave];
    unsigned short* outw = s_out[wave];

#pragma unroll
    for (int jt = 0; jt < 4; jt++) {
        short8 b0 = *(const short8*)&s_w1t[(jt * 16 + l15) * IOP + quad * 8];
        short8 bv = *(const short8*)&s_w1t[(jt * 16 + l15) * IOP + quad * 8 + 32];
        floatx4 c = {0.f, 0.f, 0.f, 0.f};
        c = __builtin_amdgcn_mfma_f32_16x16x32_bf16(a0, b0, c, 0, 0, 0);
        c = __builtin_amdgcn_mfma_f32_16x16x32_bf16(a1, bv, c, 0, 0, 0);
#pragma unroll
        for (int r = 0; r < 4; r++) {
            float v = (c[r] + bb1[jt]) * scl[jt] + sht[jt];
            v = fmaxf(v, 0.f);
            mid[(quad * 4 + r) * IOP + jt * 16 + l15] = (unsigned short)bf16_rne(v);
        }
    }
    __syncthreads();

    short8 m0 = *(const short8*)&mid[l15 * IOP + quad * 8];
    short8 m1 = *(const short8*)&mid[l15 * IOP + quad * 8 + 32];
#pragma unroll
    for (int jt = 0; jt < 4; jt++) {
        short8 b0 = *(const short8*)&s_w2t[(jt * 16 + l15) * IOP + quad * 8];
        short8 bv = *(const short8*)&s_w2t[(jt * 16 + l15) * IOP + quad * 8 + 32];
        floatx4 c = {0.f, 0.f, 0.f, 0.f};
        c = __builtin_amdgcn_mfma_f32_16x16x32_bf16(m0, b0, c, 0, 0, 0);
        c = __builtin_amdgcn_mfma_f32_16x16x32_bf16(m1, bv, c, 0, 0, 0);
#pragma unroll
        for (int r = 0; r < 4; r++) {
            float v = fmaxf(c[r] + bb2[jt], 0.f);
            outw[(quad * 4 + r) * IOP + jt * 16 + l15] = (unsigned short)bf16_rne(v);
        }
    }
    __syncthreads();

    unsigned short* ho = (unsigned short*)hout;
#pragma unroll
    for (int cc = 0; cc < 2; cc++) {
        int r = cc * 8 + (lane >> 3);
        int node = base + r;
        if (node < N_NODES) {
            short8 v = *(const short8*)&outw[r * IOP + (lane & 7) * 8];
            *(short8*)(ho + (size_t)node * H + (lane & 7) * 8) = v;
        }
    }
}

// ---------- pool (batch sorted -> range per graph) + head ----------
__global__ __launch_bounds__(192) void pool_head_kernel(
    const __hip_bfloat16* __restrict__ h1, const __hip_bfloat16* __restrict__ h2,
    const __hip_bfloat16* __restrict__ h3, const int* __restrict__ batch,
    const float* __restrict__ lin1_w, const float* __restrict__ lin1_b,
    const float* __restrict__ lin2_w, const float* __restrict__ lin2_b,
    float* __restrict__ out) {
    __shared__ float s_row[3 * H];
    __shared__ float s_mid[3 * H];
    __shared__ float s_z[C_CLS];
    __shared__ int s_se[2];

    int g = blockIdx.x;
    int j = threadIdx.x;
    if (j < 2) {
        int target = g + j;
        int lo = 0, hi = N_NODES;
        while (lo < hi) {
            int mid = (lo + hi) >> 1;
            if (batch[mid] < target) lo = mid + 1; else hi = mid;
        }
        s_se[j] = lo;
    }
    __syncthreads();
    int ns = s_se[0], ne = s_se[1];

    int which = j >> 6;
    int f = j & 63;
    const __hip_bfloat16* h = (which == 0) ? h1 : ((which == 1) ? h2 : h3);
    float p0 = 0.f, p1 = 0.f, p2 = 0.f, p3 = 0.f;
    int n = ns;
    for (; n + 3 < ne; n += 4) {
        p0 += __bfloat162float(h[(size_t)n * H + f]);
        p1 += __bfloat162float(h[(size_t)(n + 1) * H + f]);
        p2 += __bfloat162float(h[(size_t)(n + 2) * H + f]);
        p3 += __bfloat162float(h[(size_t)(n + 3) * H + f]);
    }
    for (; n < ne; n++) p0 += __bfloat162float(h[(size_t)n * H + f]);
    s_row[j] = (p0 + p1) + (p2 + p3);
    __syncthreads();

    float acc = lin1_b[j];
    for (int k = 0; k < 3 * H; k++) acc += s_row[k] * lin1_w[k * (3 * H) + j];
    s_mid[j] = fmaxf(acc, 0.f);
    __syncthreads();

    if (j < C_CLS) {
        float z = lin2_b[j];
        for (int k = 0; k < 3 * H; k++) z += s_mid[k] * lin2_w[k * C_CLS + j];
        s_z[j] = z;
    }
    __syncthreads();
    if (j < C_CLS) {
        float z0 = s_z[0], z1 = s_z[1];
        float mx = fmaxf(z0, z1);
        float lse = mx + logf(expf(z0 - mx) + expf(z1 - mx));
        out[g * C_CLS + j] = s_z[j];
        out[G_GRAPHS * C_CLS + g * C_CLS + j] = s_z[j] - lse;
    }
}

extern "C" void kernel_launch(void* const* d_in, const int* in_sizes, int n_in,
                              void* d_out, int out_size, void* d_ws, size_t ws_size,
                              hipStream_t stream) {
    const float* x = (const float*)d_in[0];
    const float* cw1[3], *cb1[3], *cg[3], *cbb[3], *cm[3], *cv[3], *cw2[3], *cb2[3];
    for (int l = 0; l < 3; l++) {
        int b = 1 + 8 * l;
        cw1[l] = (const float*)d_in[b + 0];
        cb1[l] = (const float*)d_in[b + 1];
        cg[l]  = (const float*)d_in[b + 2];
        cbb[l] = (const float*)d_in[b + 3];
        cm[l]  = (const float*)d_in[b + 4];
        cv[l]  = (const float*)d_in[b + 5];
        cw2[l] = (const float*)d_in[b + 6];
        cb2[l] = (const float*)d_in[b + 7];
    }
    const float* lin1_w = (const float*)d_in[25];
    const float* lin1_b = (const float*)d_in[26];
    const float* lin2_w = (const float*)d_in[27];
    const float* lin2_b = (const float*)d_in[28];
    const int* edge_index = (const int*)d_in[29];
    const int* batch = (const int*)d_in[30];
    const int* src = edge_index;
    const int* dst = edge_index + N_EDGES;
    float* out = (float*)d_out;

    // workspace layout
    int* edge_src = (int*)d_ws;                     // E
    int* gpacked = edge_src + N_EDGES;              // NBUCK*BUCKCAP (12.8 MB)
    int* gcnt = gpacked + (size_t)NBUCK * BUCKCAP;  // NBUCK
    int* row_start = gcnt + NBUCK;                  // N+2
    uintptr_t hp = (uintptr_t)(row_start + N_NODES + 2);
    hp = (hp + 127) & ~(uintptr_t)127;
    __hip_bfloat16* h1 = (__hip_bfloat16*)hp;       // N*H each
    __hip_bfloat16* h2 = h1 + (size_t)N_NODES * H;
    __hip_bfloat16* h3 = h2 + (size_t)N_NODES * H;
    __hip_bfloat16* xs = h3 + (size_t)N_NODES * H;

    // ---- build CSR: single-pass fixed-cap bucket scatter + per-bucket CSR ----
    hipMemsetAsync(gcnt, 0, NBUCK * sizeof(int), stream);
    scatter1_kernel<<<CSR_BLOCKS, 256, 0, stream>>>(src, dst, gcnt, gpacked);
    bcsr_kernel<<<NBUCK, 256, 0, stream>>>(gpacked, gcnt, row_start, edge_src);

    const int mlp_grid = (N_NODES + 63) / 64;   // 782

    // ---- layer 1 ----
    gather3_mid_kernel<<<N_NODES / 8, 512, 0, stream>>>(x, row_start, edge_src,
        cw1[0], cb1[0], cg[0], cbb[0], cm[0], cv[0], xs);
    matmul2_mfma_kernel<<<mlp_grid, 256, 0, stream>>>(xs, cw2[0], cb2[0], h1);
    // ---- layer 2 ----
    gather_kernel<<<N_NODES / 8, 512, 0, stream>>>(h1, row_start, edge_src, xs);
    mlp_mfma_kernel<<<mlp_grid, 256, 0, stream>>>(xs,
        cw1[1], cb1[1], cg[1], cbb[1], cm[1], cv[1], cw2[1], cb2[1], h2);
    // ---- layer 3 ----
    gather_kernel<<<N_NODES / 8, 512, 0, stream>>>(h2, row_start, edge_src, xs);
    mlp_mfma_kernel<<<mlp_grid, 256, 0, stream>>>(xs,
        cw1[2], cb1[2], cg[2], cbb[2], cm[2], cv[2], cw2[2], cb2[2], h3);
    // ---- pool + head ----
    pool_head_kernel<<<G_GRAPHS, 3 * H, 0, stream>>>(h1, h2, h3, batch,
        lin1_w, lin1_b, lin2_w, lin2_b, out);
}

// Round 16
// 279.599 us; speedup vs baseline: 1.2919x; 1.0156x over previous
//
#include <hip/hip_runtime.h>
#include <hip/hip_bf16.h>
#include <math.h>

#define N_NODES 50000
#define N_EDGES 1600000
#define H 64
#define G_GRAPHS 512
#define C_CLS 2
#define BN_EPS 1e-5f
#define NBUCK 196           // buckets of 256 nodes: dst>>8 in [0,196)
#define BUCKCAP 16384       // fixed bucket capacity (mean 8192 -> huge headroom)
#define E4 (N_EDGES / 4)    // 400000
#define CSR_BLOCKS ((E4 + 511) / 512)   // 782
#define IOP 72              // padded LDS row stride (bf16)

typedef __attribute__((ext_vector_type(8))) short short8;
typedef __attribute__((ext_vector_type(4))) float floatx4;

__device__ __forceinline__ float bflo(unsigned int u) { return __uint_as_float(u << 16); }
__device__ __forceinline__ float bfhi(unsigned int u) { return __uint_as_float(u & 0xffff0000u); }
__device__ __forceinline__ unsigned int bf16_rne(float f) {
    unsigned int u = __float_as_uint(f);
    u += 0x7fffu + ((u >> 16) & 1u);
    return u >> 16;
}

// ---------- prep: transpose 5 weight matrices to bf16 wT[j*64+k]; pack x ----------
__global__ __launch_bounds__(256) void prep_kernel(
    const float* __restrict__ w2_0, const float* __restrict__ w1_1,
    const float* __restrict__ w2_1, const float* __restrict__ w1_2,
    const float* __restrict__ w2_2, unsigned short* __restrict__ wt,
    const float* __restrict__ x, uint2* __restrict__ xb) {
    int b = blockIdx.x, t = threadIdx.x;
    if (b < 5) {
        const float* w = (b == 0) ? w2_0 : (b == 1) ? w1_1 : (b == 2) ? w2_1
                         : (b == 3) ? w1_2 : w2_2;
        unsigned short* o = wt + b * (H * H);
        for (int idx = t; idx < H * H; idx += 256) {
            int k = idx >> 6, j = idx & 63;
            o[j * H + k] = (unsigned short)bf16_rne(w[idx]);
        }
    } else {
        int node = (b - 5) * 256 + t;
        if (node < N_NODES) {
            uint2 p;
            p.x = bf16_rne(x[node * 3 + 0]) | (bf16_rne(x[node * 3 + 1]) << 16);
            p.y = bf16_rne(x[node * 3 + 2]);
            xb[node] = p;
        }
    }
}

// ---------- CSR pass 1 (single pass): scatter edges into fixed-cap buckets ----------
__global__ __launch_bounds__(256) void scatter1_kernel(const int* __restrict__ src,
                                                       const int* __restrict__ dst,
                                                       int* __restrict__ gcnt,
                                                       int* __restrict__ gpacked) {
    __shared__ int bh[NBUCK];
    int t = threadIdx.x;
    if (t < NBUCK) bh[t] = 0;
    __syncthreads();
    int base = blockIdx.x * 512;

    int pkA[4], bkA[4], lrA[4]; bool vA = false;
    int pkB[4], bkB[4], lrB[4]; bool vB = false;
    {
        int i = base + t;
        if (i < E4) {
            vA = true;
            int4 s4 = ((const int4*)src)[i];
            int4 d4 = ((const int4*)dst)[i];
            bkA[0] = d4.x >> 8; pkA[0] = ((d4.x & 255) << 16) | s4.x; lrA[0] = atomicAdd(&bh[bkA[0]], 1);
            bkA[1] = d4.y >> 8; pkA[1] = ((d4.y & 255) << 16) | s4.y; lrA[1] = atomicAdd(&bh[bkA[1]], 1);
            bkA[2] = d4.z >> 8; pkA[2] = ((d4.z & 255) << 16) | s4.z; lrA[2] = atomicAdd(&bh[bkA[2]], 1);
            bkA[3] = d4.w >> 8; pkA[3] = ((d4.w & 255) << 16) | s4.w; lrA[3] = atomicAdd(&bh[bkA[3]], 1);
        }
    }
    {
        int i = base + 256 + t;
        if (i < E4) {
            vB = true;
            int4 s4 = ((const int4*)src)[i];
            int4 d4 = ((const int4*)dst)[i];
            bkB[0] = d4.x >> 8; pkB[0] = ((d4.x & 255) << 16) | s4.x; lrB[0] = atomicAdd(&bh[bkB[0]], 1);
            bkB[1] = d4.y >> 8; pkB[1] = ((d4.y & 255) << 16) | s4.y; lrB[1] = atomicAdd(&bh[bkB[1]], 1);
            bkB[2] = d4.z >> 8; pkB[2] = ((d4.z & 255) << 16) | s4.z; lrB[2] = atomicAdd(&bh[bkB[2]], 1);
            bkB[3] = d4.w >> 8; pkB[3] = ((d4.w & 255) << 16) | s4.w; lrB[3] = atomicAdd(&bh[bkB[3]], 1);
        }
    }
    __syncthreads();
    if (t < NBUCK) {
        int c = bh[t];
        bh[t] = c ? atomicAdd(&gcnt[t], c) : 0;
    }
    __syncthreads();
    if (vA) {
#pragma unroll
        for (int q = 0; q < 4; q++) gpacked[bkA[q] * BUCKCAP + bh[bkA[q]] + lrA[q]] = pkA[q];
    }
    if (vB) {
#pragma unroll
        for (int q = 0; q < 4; q++) gpacked[bkB[q] * BUCKCAP + bh[bkB[q]] + lrB[q]] = pkB[q];
    }
}

// ---------- CSR pass 2: per-bucket local CSR; bucket offset computed in-block ----------
__global__ __launch_bounds__(256) void bcsr_kernel(const int* __restrict__ gpacked,
                                                   const int* __restrict__ gcnt,
                                                   int* __restrict__ row_start,
                                                   int* __restrict__ edge_src) {
    __shared__ int cnt[256];
    __shared__ int pref[256];
    int b = blockIdx.x;
    int t = threadIdx.x;

    int v = (t < NBUCK) ? gcnt[t] : 0;
    pref[t] = v;
    __syncthreads();
    for (int off = 1; off < 256; off <<= 1) {
        int u = 0;
        if (t >= off) u = pref[t - off];
        __syncthreads();
        if (t >= off) pref[t] += u;
        __syncthreads();
    }
    int bs = (b > 0) ? pref[b - 1] : 0;
    int cnt_b = gcnt[b];
    if (b == 0 && t == 0) row_start[N_NODES] = N_EDGES;
    __syncthreads();

    const int* gp = gpacked + (size_t)b * BUCKCAP;
    cnt[t] = 0;
    __syncthreads();
    for (int i = t; i < cnt_b; i += 256) atomicAdd(&cnt[gp[i] >> 16], 1);
    __syncthreads();
    int c = cnt[t];
    pref[t] = c;
    __syncthreads();
    for (int off = 1; off < 256; off <<= 1) {
        int u = 0;
        if (t >= off) u = pref[t - off];
        __syncthreads();
        if (t >= off) pref[t] += u;
        __syncthreads();
    }
    int excl = pref[t] - c;
    int node = b * 256 + t;
    if (node < N_NODES) row_start[node] = bs + excl;
    cnt[t] = excl;
    __syncthreads();
    for (int i = t; i < cnt_b; i += 256) {
        int p = gp[i];
        int pos = atomicAdd(&cnt[p >> 16], 1);
        edge_src[bs + pos] = p & 0xffff;
    }
}

// ---------- layer 1 fused: 16 nodes/block, 2 nodes/wave gather+lin1, wave0 MFMA lin2 ----------
__global__ __launch_bounds__(512) void gin1_fused16_kernel(
    const float* __restrict__ x, const uint2* __restrict__ xb,
    const int* __restrict__ row_start, const int* __restrict__ edge_src,
    const float* __restrict__ w1, const float* __restrict__ b1,
    const float* __restrict__ bn_g, const float* __restrict__ bn_b,
    const float* __restrict__ bn_m, const float* __restrict__ bn_v,
    const unsigned short* __restrict__ w2t, const float* __restrict__ b2,
    __hip_bfloat16* __restrict__ hout) {
    __shared__ unsigned short s_mid[16 * IOP];

    int tid = threadIdx.x;
    int wave = tid >> 6, j = tid & 63;
    int nodebase = blockIdx.x * 16;     // 3125 blocks x 16 = 50000 exact

    float wj0 = w1[j], wj1 = w1[H + j], wj2 = w1[2 * H + j];
    float sc = rsqrtf(bn_v[j] + BN_EPS) * bn_g[j];
    float sh = bn_b[j] - bn_m[j] * sc;
    float bj = b1[j];

    // phase A: each wave gathers+lin1 its 2 nodes
    for (int nl = wave * 2; nl < wave * 2 + 2; nl++) {
        int node = nodebase + nl;
        int rs = row_start[node], re = row_start[node + 1];
        float a0 = 0.f, a1 = 0.f, a2 = 0.f;
        for (int t = rs + j; t < re; t += 64) {
            uint2 p = xb[edge_src[t]];
            a0 += bflo(p.x); a1 += bfhi(p.x); a2 += bflo(p.y);
        }
#pragma unroll
        for (int off = 32; off > 0; off >>= 1) {
            a0 += __shfl_xor(a0, off);
            a1 += __shfl_xor(a1, off);
            a2 += __shfl_xor(a2, off);
        }
        float in0 = a0 + x[node * 3 + 0];
        float in1 = a1 + x[node * 3 + 1];
        float in2 = a2 + x[node * 3 + 2];
        float m = bj + in0 * wj0 + in1 * wj1 + in2 * wj2;
        m = fmaxf(m * sc + sh, 0.f);
        s_mid[nl * IOP + j] = (unsigned short)bf16_rne(m);
    }
    __syncthreads();

    // phase B: wave 0 computes relu(mid@w2+b2) for all 16 nodes and stores
    if (wave == 0) {
        int quad = j >> 4, l15 = j & 15;
        float bb2[4];
#pragma unroll
        for (int jt = 0; jt < 4; jt++) bb2[jt] = b2[jt * 16 + l15];

        short8 m0 = *(const short8*)&s_mid[l15 * IOP + quad * 8];
        short8 m1 = *(const short8*)&s_mid[l15 * IOP + quad * 8 + 32];
#pragma unroll
        for (int jt = 0; jt < 4; jt++) {
            short8 b0 = *(const short8*)&w2t[(jt * 16 + l15) * H + quad * 8];
            short8 bv = *(const short8*)&w2t[(jt * 16 + l15) * H + quad * 8 + 32];
            floatx4 c = {0.f, 0.f, 0.f, 0.f};
            c = __builtin_amdgcn_mfma_f32_16x16x32_bf16(m0, b0, c, 0, 0, 0);
            c = __builtin_amdgcn_mfma_f32_16x16x32_bf16(m1, bv, c, 0, 0, 0);
#pragma unroll
            for (int r = 0; r < 4; r++) {
                float v = fmaxf(c[r] + bb2[jt], 0.f);
                s_mid[(quad * 4 + r) * IOP + jt * 16 + l15] = (unsigned short)bf16_rne(v);
            }
        }
        unsigned short* ho = (unsigned short*)hout;
#pragma unroll
        for (int cc = 0; cc < 2; cc++) {
            int r = cc * 8 + (j >> 3);
            short8 v = *(const short8*)&s_mid[r * IOP + (j & 7) * 8];
            *(short8*)(ho + (size_t)(nodebase + r) * H + (j & 7) * 8) = v;
        }
    }
}

// ---------- layers 2/3 fused: 16 nodes/block, 2 nodes/wave gather, wave0 MFMA MLP ----------
__global__ __launch_bounds__(512) void gin_fused16_kernel(
    const __hip_bfloat16* __restrict__ hin, const int* __restrict__ row_start,
    const int* __restrict__ edge_src,
    const unsigned short* __restrict__ w1t, const float* __restrict__ b1,
    const float* __restrict__ bn_g, const float* __restrict__ bn_b,
    const float* __restrict__ bn_m, const float* __restrict__ bn_v,
    const unsigned short* __restrict__ w2t, const float* __restrict__ b2,
    __hip_bfloat16* __restrict__ hout) {
    __shared__ unsigned short s_xs[16 * IOP];
    __shared__ unsigned short s_mid[16 * IOP];

    int tid = threadIdx.x;
    int wave = tid >> 6, j = tid & 63;
    int o = j >> 3, jo = j & 7;
    int nodebase = blockIdx.x * 16;

    const char* hb = (const char*)hin;

    // phase A: each wave gathers its 2 nodes (octet scheme, 2x unroll)
    for (int nl = wave * 2; nl < wave * 2 + 2; nl++) {
        int node = nodebase + nl;
        int rs = row_start[node], re = row_start[node + 1];
        float a0 = 0.f, a1 = 0.f, a2 = 0.f, a3 = 0.f, a4 = 0.f, a5 = 0.f, a6 = 0.f, a7 = 0.f;
        float b0 = 0.f, b1v = 0.f, b2v = 0.f, b3 = 0.f, b4 = 0.f, b5 = 0.f, b6 = 0.f, b7 = 0.f;
        for (int base = rs; base < re; base += 64) {
            int idx = base + j;
            int sv = (idx < re) ? edge_src[idx] : 0;
            int cnt = min(64, re - base);
            int i = 0;
            for (; i + 16 <= cnt; i += 16) {
                int s0 = __shfl(sv, i + o);
                int s1 = __shfl(sv, i + 8 + o);
                uint4 r0 = *(const uint4*)(hb + (size_t)s0 * 128 + jo * 16);
                uint4 r1 = *(const uint4*)(hb + (size_t)s1 * 128 + jo * 16);
                a0 += bflo(r0.x); a1 += bfhi(r0.x);
                a2 += bflo(r0.y); a3 += bfhi(r0.y);
                a4 += bflo(r0.z); a5 += bfhi(r0.z);
                a6 += bflo(r0.w); a7 += bfhi(r0.w);
                b0 += bflo(r1.x); b1v += bfhi(r1.x);
                b2v += bflo(r1.y); b3 += bfhi(r1.y);
                b4 += bflo(r1.z); b5 += bfhi(r1.z);
                b6 += bflo(r1.w); b7 += bfhi(r1.w);
            }
            for (; i + 8 <= cnt; i += 8) {
                int s = __shfl(sv, i + o);
                uint4 raw = *(const uint4*)(hb + (size_t)s * 128 + jo * 16);
                a0 += bflo(raw.x); a1 += bfhi(raw.x);
                a2 += bflo(raw.y); a3 += bfhi(raw.y);
                a4 += bflo(raw.z); a5 += bfhi(raw.z);
                a6 += bflo(raw.w); a7 += bfhi(raw.w);
            }
            if (i < cnt) {
                int r = cnt - i;
                int s = __shfl(sv, i + (o < r ? o : 0));
                uint4 raw = *(const uint4*)(hb + (size_t)s * 128 + jo * 16);
                if (o < r) {
                    a0 += bflo(raw.x); a1 += bfhi(raw.x);
                    a2 += bflo(raw.y); a3 += bfhi(raw.y);
                    a4 += bflo(raw.z); a5 += bfhi(raw.z);
                    a6 += bflo(raw.w); a7 += bfhi(raw.w);
                }
            }
        }
        a0 += b0; a1 += b1v; a2 += b2v; a3 += b3;
        a4 += b4; a5 += b5; a6 += b6; a7 += b7;
        a0 += __shfl_xor(a0, 8); a0 += __shfl_xor(a0, 16); a0 += __shfl_xor(a0, 32);
        a1 += __shfl_xor(a1, 8); a1 += __shfl_xor(a1, 16); a1 += __shfl_xor(a1, 32);
        a2 += __shfl_xor(a2, 8); a2 += __shfl_xor(a2, 16); a2 += __shfl_xor(a2, 32);
        a3 += __shfl_xor(a3, 8); a3 += __shfl_xor(a3, 16); a3 += __shfl_xor(a3, 32);
        a4 += __shfl_xor(a4, 8); a4 += __shfl_xor(a4, 16); a4 += __shfl_xor(a4, 32);
        a5 += __shfl_xor(a5, 8); a5 += __shfl_xor(a5, 16); a5 += __shfl_xor(a5, 32);
        a6 += __shfl_xor(a6, 8); a6 += __shfl_xor(a6, 16); a6 += __shfl_xor(a6, 32);
        a7 += __shfl_xor(a7, 8); a7 += __shfl_xor(a7, 16); a7 += __shfl_xor(a7, 32);
        if (o == 0) {
            uint4 raw = *(const uint4*)(hb + (size_t)node * 128 + jo * 16);
            a0 += bflo(raw.x); a1 += bfhi(raw.x);
            a2 += bflo(raw.y); a3 += bfhi(raw.y);
            a4 += bflo(raw.z); a5 += bfhi(raw.z);
            a6 += bflo(raw.w); a7 += bfhi(raw.w);
            uint4 ov;
            ov.x = bf16_rne(a0) | (bf16_rne(a1) << 16);
            ov.y = bf16_rne(a2) | (bf16_rne(a3) << 16);
            ov.z = bf16_rne(a4) | (bf16_rne(a5) << 16);
            ov.w = bf16_rne(a6) | (bf16_rne(a7) << 16);
            *(uint4*)&s_xs[nl * IOP + jo * 8] = ov;
        }
    }
    __syncthreads();

    // phase B: wave 0 runs the full MLP for all 16 nodes
    if (wave == 0) {
        int quad = j >> 4, l15 = j & 15;
        float scl[4], sht[4], bb1[4], bb2[4];
#pragma unroll
        for (int jt = 0; jt < 4; jt++) {
            int jj = jt * 16 + l15;
            float sc = rsqrtf(bn_v[jj] + BN_EPS) * bn_g[jj];
            scl[jt] = sc;
            sht[jt] = bn_b[jj] - bn_m[jj] * sc;
            bb1[jt] = b1[jj];
            bb2[jt] = b2[jj];
        }
        short8 a0 = *(const short8*)&s_xs[l15 * IOP + quad * 8];
        short8 a1 = *(const short8*)&s_xs[l15 * IOP + quad * 8 + 32];
#pragma unroll
        for (int jt = 0; jt < 4; jt++) {
            short8 b0 = *(const short8*)&w1t[(jt * 16 + l15) * H + quad * 8];
            short8 bv = *(const short8*)&w1t[(jt * 16 + l15) * H + quad * 8 + 32];
            floatx4 c = {0.f, 0.f, 0.f, 0.f};
            c = __builtin_amdgcn_mfma_f32_16x16x32_bf16(a0, b0, c, 0, 0, 0);
            c = __builtin_amdgcn_mfma_f32_16x16x32_bf16(a1, bv, c, 0, 0, 0);
#pragma unroll
            for (int r = 0; r < 4; r++) {
                float v = (c[r] + bb1[jt]) * scl[jt] + sht[jt];
                v = fmaxf(v, 0.f);
                s_mid[(quad * 4 + r) * IOP + jt * 16 + l15] = (unsigned short)bf16_rne(v);
            }
        }
        short8 m0 = *(const short8*)&s_mid[l15 * IOP + quad * 8];
        short8 m1 = *(const short8*)&s_mid[l15 * IOP + quad * 8 + 32];
#pragma unroll
        for (int jt = 0; jt < 4; jt++) {
            short8 b0 = *(const short8*)&w2t[(jt * 16 + l15) * H + quad * 8];
            short8 bv = *(const short8*)&w2t[(jt * 16 + l15) * H + quad * 8 + 32];
            floatx4 c = {0.f, 0.f, 0.f, 0.f};
            c = __builtin_amdgcn_mfma_f32_16x16x32_bf16(m0, b0, c, 0, 0, 0);
            c = __builtin_amdgcn_mfma_f32_16x16x32_bf16(m1, bv, c, 0, 0, 0);
#pragma unroll
            for (int r = 0; r < 4; r++) {
                float v = fmaxf(c[r] + bb2[jt], 0.f);
                s_xs[(quad * 4 + r) * IOP + jt * 16 + l15] = (unsigned short)bf16_rne(v);
            }
        }
        unsigned short* ho = (unsigned short*)hout;
#pragma unroll
        for (int cc = 0; cc < 2; cc++) {
            int r = cc * 8 + (j >> 3);
            short8 v = *(const short8*)&s_xs[r * IOP + (j & 7) * 8];
            *(short8*)(ho + (size_t)(nodebase + r) * H + (j & 7) * 8) = v;
        }
    }
}

// ---------- pool (batch sorted -> range per graph) + head ----------
__global__ __launch_bounds__(192) void pool_head_kernel(
    const __hip_bfloat16* __restrict__ h1, const __hip_bfloat16* __restrict__ h2,
    const __hip_bfloat16* __restrict__ h3, const int* __restrict__ batch,
    const float* __restrict__ lin1_w, const float* __restrict__ lin1_b,
    const float* __restrict__ lin2_w, const float* __restrict__ lin2_b,
    float* __restrict__ out) {
    __shared__ float s_row[3 * H];
    __shared__ float s_mid[3 * H];
    __shared__ float s_z[C_CLS];
    __shared__ int s_se[2];

    int g = blockIdx.x;
    int j = threadIdx.x;
    if (j < 2) {
        int target = g + j;
        int lo = 0, hi = N_NODES;
        while (lo < hi) {
            int mid = (lo + hi) >> 1;
            if (batch[mid] < target) lo = mid + 1; else hi = mid;
        }
        s_se[j] = lo;
    }
    __syncthreads();
    int ns = s_se[0], ne = s_se[1];

    int which = j >> 6;
    int f = j & 63;
    const __hip_bfloat16* h = (which == 0) ? h1 : ((which == 1) ? h2 : h3);
    float p0 = 0.f, p1 = 0.f, p2 = 0.f, p3 = 0.f;
    int n = ns;
    for (; n + 3 < ne; n += 4) {
        p0 += __bfloat162float(h[(size_t)n * H + f]);
        p1 += __bfloat162float(h[(size_t)(n + 1) * H + f]);
        p2 += __bfloat162float(h[(size_t)(n + 2) * H + f]);
        p3 += __bfloat162float(h[(size_t)(n + 3) * H + f]);
    }
    for (; n < ne; n++) p0 += __bfloat162float(h[(size_t)n * H + f]);
    s_row[j] = (p0 + p1) + (p2 + p3);
    __syncthreads();

    float acc = lin1_b[j];
    for (int k = 0; k < 3 * H; k++) acc += s_row[k] * lin1_w[k * (3 * H) + j];
    s_mid[j] = fmaxf(acc, 0.f);
    __syncthreads();

    if (j < C_CLS) {
        float z = lin2_b[j];
        for (int k = 0; k < 3 * H; k++) z += s_mid[k] * lin2_w[k * C_CLS + j];
        s_z[j] = z;
    }
    __syncthreads();
    if (j < C_CLS) {
        float z0 = s_z[0], z1 = s_z[1];
        float mx = fmaxf(z0, z1);
        float lse = mx + logf(expf(z0 - mx) + expf(z1 - mx));
        out[g * C_CLS + j] = s_z[j];
        out[G_GRAPHS * C_CLS + g * C_CLS + j] = s_z[j] - lse;
    }
}

extern "C" void kernel_launch(void* const* d_in, const int* in_sizes, int n_in,
                              void* d_out, int out_size, void* d_ws, size_t ws_size,
                              hipStream_t stream) {
    const float* x = (const float*)d_in[0];
    const float* cw1[3], *cb1[3], *cg[3], *cbb[3], *cm[3], *cv[3], *cw2[3], *cb2[3];
    for (int l = 0; l < 3; l++) {
        int b = 1 + 8 * l;
        cw1[l] = (const float*)d_in[b + 0];
        cb1[l] = (const float*)d_in[b + 1];
        cg[l]  = (const float*)d_in[b + 2];
        cbb[l] = (const float*)d_in[b + 3];
        cm[l]  = (const float*)d_in[b + 4];
        cv[l]  = (const float*)d_in[b + 5];
        cw2[l] = (const float*)d_in[b + 6];
        cb2[l] = (const float*)d_in[b + 7];
    }
    const float* lin1_w = (const float*)d_in[25];
    const float* lin1_b = (const float*)d_in[26];
    const float* lin2_w = (const float*)d_in[27];
    const float* lin2_b = (const float*)d_in[28];
    const int* edge_index = (const int*)d_in[29];
    const int* batch = (const int*)d_in[30];
    const int* src = edge_index;
    const int* dst = edge_index + N_EDGES;
    float* out = (float*)d_out;

    // workspace layout
    int* edge_src = (int*)d_ws;                     // E
    int* gpacked = edge_src + N_EDGES;              // NBUCK*BUCKCAP (12.8 MB)
    int* gcnt = gpacked + (size_t)NBUCK * BUCKCAP;  // NBUCK
    int* row_start = gcnt + NBUCK;                  // N+2
    uintptr_t hp = (uintptr_t)(row_start + N_NODES + 2);
    hp = (hp + 127) & ~(uintptr_t)127;
    unsigned short* wt = (unsigned short*)hp;       // 5 * H*H bf16
    uint2* xb = (uint2*)(wt + 5 * H * H);           // N
    __hip_bfloat16* h1 = (__hip_bfloat16*)(xb + N_NODES);  // N*H each
    __hip_bfloat16* h2 = h1 + (size_t)N_NODES * H;
    __hip_bfloat16* h3 = h2 + (size_t)N_NODES * H;

    const unsigned short* w2t_0 = wt + 0 * H * H;
    const unsigned short* w1t_1 = wt + 1 * H * H;
    const unsigned short* w2t_1 = wt + 2 * H * H;
    const unsigned short* w1t_2 = wt + 3 * H * H;
    const unsigned short* w2t_2 = wt + 4 * H * H;

    // ---- prep + CSR build ----
    hipMemsetAsync(gcnt, 0, NBUCK * sizeof(int), stream);
    prep_kernel<<<5 + (N_NODES + 255) / 256, 256, 0, stream>>>(
        cw2[0], cw1[1], cw2[1], cw1[2], cw2[2], wt, x, xb);
    scatter1_kernel<<<CSR_BLOCKS, 256, 0, stream>>>(src, dst, gcnt, gpacked);
    bcsr_kernel<<<NBUCK, 256, 0, stream>>>(gpacked, gcnt, row_start, edge_src);

    const int fgrid = N_NODES / 16;   // 3125, exact

    // ---- layer 1 ----
    gin1_fused16_kernel<<<fgrid, 512, 0, stream>>>(x, xb, row_start, edge_src,
        cw1[0], cb1[0], cg[0], cbb[0], cm[0], cv[0], w2t_0, cb2[0], h1);
    // ---- layer 2 ----
    gin_fused16_kernel<<<fgrid, 512, 0, stream>>>(h1, row_start, edge_src,
        w1t_1, cb1[1], cg[1], cbb[1], cm[1], cv[1], w2t_1, cb2[1], h2);
    // ---- layer 3 ----
    gin_fused16_kernel<<<fgrid, 512, 0, stream>>>(h2, row_start, edge_src,
        w1t_2, cb1[2], cg[2], cbb[2], cm[2], cv[2], w2t_2, cb2[2], h3);
    // ---- pool + head ----
    pool_head_kernel<<<G_GRAPHS, 3 * H, 0, stream>>>(h1, h2, h3, batch,
        lin1_w, lin1_b, lin2_w, lin2_b, out);
}